// Round 9
// baseline (2117.640 us; speedup 1.0000x reference)
//
#include <hip/hip_runtime.h>
#include <stdint.h>

#define N_NODES 50000
#define N_EDGES 800000
#define B_GRAPHS 64
#define D_DIM 64
#define HD 128
#define G_GAUSS 50
#define HID_DIM 128
#define L_LAYERS 3
#define LN2 0.69314718055994530942f
#define PI_OVER_8 0.39269908169872414f
#define NCHUNK 196            // ceil(50000/256)

#define TN 64                 // nodes per node-GEMM block
#define TLD 132               // fp32 LDS leading dim for 128-wide tiles
#define XLD 68                // fp32 LDS leading dim for 64-wide tiles
#define NBLK ((N_NODES + TN - 1) / TN)   // 782

// filter-net lookup table: w(r)*C(r) over r in [0,8), linear interpolation.
// Rows 0..LUT_T-1 cover [0,8); row LUT_T is all-zero (r>=8 cutoff folded in).
#define LUT_T 2048
#define LUT_ROWS (LUT_T + 1)
#define LROWS 8               // table rows built per block

__device__ __forceinline__ float sspf(float x) {
    float ax = fabsf(x);
    return fmaxf(x, 0.f) + __logf(1.f + __expf(-ax)) - LN2;
}
__device__ __forceinline__ unsigned short f2bf(float f) {
    union { float f; unsigned int i; } v; v.f = f;
    unsigned int u = v.i;
    return (unsigned short)((u + 0x7FFFu + ((u >> 16) & 1u)) >> 16);
}

// ------------- one-time: zero edge counter + output -------------
__global__ void repr_prep(int* __restrict__ count, float* __restrict__ dout) {
    int i = blockIdx.x * 256 + threadIdx.x;
    if (i < N_NODES) count[i] = 0;
    else if (i < N_NODES + B_GRAPHS) dout[i - N_NODES] = 0.f;
}

// ------------- one-time: build wc(r) = (ssp(gs@W1+b1)@W2 + b2) * C(r) table -------------
// interleaved bf16: lut[l][i][c] = bf16(wc[i][c]) | bf16(wc[i+1][c])<<16
__global__ __launch_bounds__(256) void repr_lut_build(
    const float* __restrict__ offs, const float* __restrict__ widths,
    const float* __restrict__ fw1, const float* __restrict__ fb1,
    const float* __restrict__ fw2, const float* __restrict__ fb2,
    unsigned int* __restrict__ lut)
{
    __shared__ float gs_s[LROWS + 1][G_GAUSS];
    __shared__ float hid_s[LROWS + 1][HID_DIM];
    __shared__ float wc_s[LROWS + 1][HD];
    const int nb = LUT_T / LROWS;            // 256 blocks per layer
    int l = blockIdx.x / nb;
    int i0r = (blockIdx.x % nb) * LROWS;
    int tid = threadIdx.x;
    const float step = 8.0f / LUT_T;

    for (int j = tid; j < (LROWS + 1) * G_GAUSS; j += 256) {
        int r = j / G_GAUSS, k = j - r * G_GAUSS;
        float rr = (i0r + r) * step;
        float wdt = widths[k];
        float dr = rr - offs[k];
        gs_s[r][k] = expf(-0.5f / (wdt * wdt) * dr * dr);
    }
    __syncthreads();

    int c = tid & 127, sub = tid >> 7;
    int rlo = sub * 4;                       // rows 0..4 / 4..8 (row 4 dup, benign)
    {
        const float* W1 = fw1 + (size_t)l * G_GAUSS * HID_DIM + c;
        float acc[5];
        float bb = fb1[l * HID_DIM + c];
        #pragma unroll
        for (int r = 0; r < 5; r++) acc[r] = bb;
        for (int k = 0; k < G_GAUSS; k++) {
            float wv = W1[k * HID_DIM];
            #pragma unroll
            for (int r = 0; r < 5; r++)
                acc[r] = fmaf(gs_s[rlo + r][k], wv, acc[r]);
        }
        #pragma unroll
        for (int r = 0; r < 5; r++) hid_s[rlo + r][c] = sspf(acc[r]);
    }
    __syncthreads();
    {
        const float* W2 = fw2 + (size_t)l * HID_DIM * HD + c;
        float acc[5];
        float bb = fb2[l * HD + c];
        #pragma unroll
        for (int r = 0; r < 5; r++) acc[r] = bb;
        for (int k = 0; k < HID_DIM; k++) {
            float wv = W2[k * HD];
            #pragma unroll
            for (int r = 0; r < 5; r++)
                acc[r] = fmaf(hid_s[rlo + r][k], wv, acc[r]);
        }
        #pragma unroll
        for (int r = 0; r < 5; r++) {
            float rr = (i0r + rlo + r) * step;
            float C = (rr < 8.0f) ? 0.5f * (cosf(rr * PI_OVER_8) + 1.f) : 0.f;
            wc_s[rlo + r][c] = acc[r] * C;
        }
    }
    __syncthreads();
    for (int j = tid; j < LROWS * HD; j += 256) {
        int r = j >> 7, cc = j & 127;
        unsigned int lo = f2bf(wc_s[r][cc]);
        unsigned int hi = f2bf(wc_s[r + 1][cc]);
        lut[((size_t)l * LUT_ROWS + i0r + r) * HD + cc] = lo | (hi << 16);
    }
    // last block of each layer writes the zeros row (r >= 8 cutoff)
    if (i0r == LUT_T - LROWS && tid < HD)
        lut[((size_t)l * LUT_ROWS + LUT_T) * HD + tid] = 0u;
}

// ------------- histogram + pack {src|dst<<16, r fixed-point} per edge -------------
__global__ void repr_hist(const float* __restrict__ R,
                          const int* __restrict__ src, const int* __restrict__ dst,
                          int* __restrict__ count,
                          int2* __restrict__ pk) {
    int e = blockIdx.x * blockDim.x + threadIdx.x;
    if (e >= N_EDGES) return;
    int s = src[e], d = dst[e];
    float dx = R[3*s+0] - R[3*d+0];
    float dy = R[3*s+1] - R[3*d+1];
    float dz = R[3*s+2] - R[3*d+2];
    float r = sqrtf(dx*dx + dy*dy + dz*dz);
    // r*2^24; i0 = rf>>16 in [0,2047] for r<8, else 2048 -> zeros row
    unsigned rf = (r < 8.0f) ? (unsigned)(r * 16777216.f) : (2048u << 16);
    if (rf > (2048u << 16)) rf = 2048u << 16;
    pk[e] = make_int2((int)((unsigned)s | ((unsigned)d << 16)), (int)rf);
    atomicAdd(&count[d], 1);
}

// ------------- 2-level exclusive scan over 50000 counts -------------
__global__ void repr_scanA(const int* __restrict__ cnt, int* __restrict__ excl,
                           int* __restrict__ bsum) {
    __shared__ int tmp[256];
    int t = threadIdx.x, b = blockIdx.x;
    int i = b * 256 + t;
    int v = (i < N_NODES) ? cnt[i] : 0;
    tmp[t] = v; __syncthreads();
    for (int off = 1; off < 256; off <<= 1) {
        int add = (t >= off) ? tmp[t - off] : 0;
        __syncthreads();
        tmp[t] += add;
        __syncthreads();
    }
    if (i < N_NODES) excl[i] = tmp[t] - v;
    if (t == 255) bsum[b] = tmp[255];
}
__global__ void repr_scanB(const int* __restrict__ bsum, int* __restrict__ bpref) {
    __shared__ int tmp[256];
    int t = threadIdx.x;
    int v = (t < NCHUNK) ? bsum[t] : 0;
    tmp[t] = v; __syncthreads();
    for (int off = 1; off < 256; off <<= 1) {
        int add = (t >= off) ? tmp[t - off] : 0;
        __syncthreads();
        tmp[t] += add;
        __syncthreads();
    }
    if (t < NCHUNK) bpref[t] = tmp[t] - v;
}
__global__ void repr_scanC(const int* __restrict__ excl, const int* __restrict__ bpref,
                           int* __restrict__ cur, int* __restrict__ rowptr) {
    int i = blockIdx.x * 256 + threadIdx.x;
    if (i < N_NODES) { int v = excl[i] + bpref[blockIdx.x]; cur[i] = v; rowptr[i] = v; }
    if (i == 0) rowptr[N_NODES] = N_EDGES;
}

// ------------- scatter: dst-sorted packed edge list, one 8B store per edge -------------
__global__ void repr_scatter(const int2* __restrict__ pk,
                             int* __restrict__ cur,
                             int2* __restrict__ surv) {
    int e = blockIdx.x * blockDim.x + threadIdx.x;
    if (e >= N_EDGES) return;
    int2 v = pk[e];
    int d = (int)((unsigned)v.x >> 16);
    int pos = atomicAdd(&cur[d], 1);
    surv[pos] = v;
}

// ================= tiled fp32 node GEMMs (64 nodes / block, 256 threads) =================

// agg holds UNNORMALIZED weighted sums; divide by denom[d] here (deferred softmax).
__device__ __forceinline__ void load_ssp_agg(int base, int tid,
        const float* __restrict__ agg, const float* __restrict__ denom,
        float* __restrict__ bufA) {
    int row = tid >> 2;
    int c0 = (tid & 3) << 5;
    int n = base + row;
    float2 dn = *(const float2*)&denom[2 * (size_t)n];
    float i0v = dn.x > 0.f ? 1.f / dn.x : 0.f;
    float i1v = dn.y > 0.f ? 1.f / dn.y : 0.f;
    float inv = (c0 < 64) ? i0v : i1v;
    const float* ap = agg + (size_t)n * HD + c0;
    float* tp = bufA + row * TLD + c0;
    #pragma unroll
    for (int j = 0; j < 8; j++) {
        float4 v = *(const float4*)(ap + j * 4);
        tp[j*4+0] = sspf(v.x * inv); tp[j*4+1] = sspf(v.y * inv);
        tp[j*4+2] = sspf(v.z * inv); tp[j*4+3] = sspf(v.w * inv);
    }
}

__device__ __forceinline__ void gemm_mlp(int base, int tid,
        const float* __restrict__ w1, const float* __restrict__ b1,
        const float* __restrict__ w2, const float* __restrict__ b2,
        float* __restrict__ x, float* __restrict__ bufA, float* __restrict__ v1s)
{
    const int rg = tid >> 4, cg = tid & 15;
    const int r0 = rg * 4, c0 = cg * 4;
    float acc[4][4];
    #pragma unroll
    for (int r = 0; r < 4; r++)
        #pragma unroll
        for (int c = 0; c < 4; c++) acc[r][c] = 0.f;
    for (int k0 = 0; k0 < 128; k0 += 4) {
        float av[4][4];
        #pragma unroll
        for (int r = 0; r < 4; r++)
            *(float4*)av[r] = *(const float4*)&bufA[(r0 + r) * TLD + k0];
        #pragma unroll
        for (int kk = 0; kk < 4; kk++) {
            float4 wv = *(const float4*)(w1 + (k0 + kk) * 64 + c0);
            float wf[4] = {wv.x, wv.y, wv.z, wv.w};
            #pragma unroll
            for (int r = 0; r < 4; r++)
                #pragma unroll
                for (int c = 0; c < 4; c++)
                    acc[r][c] = fmaf(av[r][kk], wf[c], acc[r][c]);
        }
    }
    {
        float4 bv = *(const float4*)(b1 + c0);
        float ba[4] = {bv.x, bv.y, bv.z, bv.w};
        #pragma unroll
        for (int r = 0; r < 4; r++)
            #pragma unroll
            for (int c = 0; c < 4; c++)
                v1s[(r0 + r) * XLD + c0 + c] = sspf(acc[r][c] + ba[c]);
    }
    __syncthreads();
    float acc2[4][4];
    #pragma unroll
    for (int r = 0; r < 4; r++)
        #pragma unroll
        for (int c = 0; c < 4; c++) acc2[r][c] = 0.f;
    for (int k0 = 0; k0 < 64; k0 += 4) {
        float av[4][4];
        #pragma unroll
        for (int r = 0; r < 4; r++)
            *(float4*)av[r] = *(const float4*)&v1s[(r0 + r) * XLD + k0];
        #pragma unroll
        for (int kk = 0; kk < 4; kk++) {
            float4 wv = *(const float4*)(w2 + (k0 + kk) * 64 + c0);
            float wf[4] = {wv.x, wv.y, wv.z, wv.w};
            #pragma unroll
            for (int r = 0; r < 4; r++)
                #pragma unroll
                for (int c = 0; c < 4; c++)
                    acc2[r][c] = fmaf(av[r][kk], wf[c], acc2[r][c]);
        }
    }
    {
        float4 bv = *(const float4*)(b2 + c0);
        #pragma unroll
        for (int r = 0; r < 4; r++) {
            int n = base + r0 + r;
            float4 xv = *(const float4*)(x + (size_t)n * 64 + c0);
            float4 o;
            o.x = acc2[r][0] + bv.x + xv.x;
            o.y = acc2[r][1] + bv.y + xv.y;
            o.z = acc2[r][2] + bv.z + xv.z;
            o.w = acc2[r][3] + bv.w + xv.w;
            *(float4*)&bufA[(r0 + r) * XLD + c0] = o;
            if (n < N_NODES) *(float4*)(x + (size_t)n * 64 + c0) = o;
        }
    }
    __syncthreads();
}

// h stored packed bf16: hq[n*64 + c/2] = bf16(h[c]) | bf16(h[c+1])<<16
__device__ __forceinline__ void gemm_h(int base, int tid,
        const float* __restrict__ bufA,
        const float* __restrict__ fc_w, const float* __restrict__ attn_l,
        const float* __restrict__ attn_r,
        unsigned int* __restrict__ hq, float* __restrict__ el, float* __restrict__ er)
{
    const int rg = tid >> 4, cg = tid & 15;
    const int r0 = rg * 4, c0 = cg * 8;
    float acc[4][8];
    #pragma unroll
    for (int r = 0; r < 4; r++)
        #pragma unroll
        for (int c = 0; c < 8; c++) acc[r][c] = 0.f;
    for (int k0 = 0; k0 < 64; k0 += 4) {
        float av[4][4];
        #pragma unroll
        for (int r = 0; r < 4; r++)
            *(float4*)av[r] = *(const float4*)&bufA[(r0 + r) * XLD + k0];
        #pragma unroll
        for (int kk = 0; kk < 4; kk++) {
            float4 w0 = *(const float4*)(fc_w + (k0 + kk) * 128 + c0);
            float4 w1v = *(const float4*)(fc_w + (k0 + kk) * 128 + c0 + 4);
            float wf[8] = {w0.x, w0.y, w0.z, w0.w, w1v.x, w1v.y, w1v.z, w1v.w};
            #pragma unroll
            for (int r = 0; r < 4; r++)
                #pragma unroll
                for (int c = 0; c < 8; c++)
                    acc[r][c] = fmaf(av[r][kk], wf[c], acc[r][c]);
        }
    }
    float al[8], ar[8];
    #pragma unroll
    for (int c = 0; c < 8; c++) { al[c] = attn_l[c0 + c]; ar[c] = attn_r[c0 + c]; }
    int head = cg >> 3;
    #pragma unroll
    for (int r = 0; r < 4; r++) {
        int n = base + r0 + r;
        float pel = 0.f, per = 0.f;
        #pragma unroll
        for (int c = 0; c < 8; c++) {
            pel = fmaf(acc[r][c], al[c], pel);
            per = fmaf(acc[r][c], ar[c], per);
        }
        if (n < N_NODES) {
            uint4 pv;
            pv.x = (unsigned int)f2bf(acc[r][0]) | ((unsigned int)f2bf(acc[r][1]) << 16);
            pv.y = (unsigned int)f2bf(acc[r][2]) | ((unsigned int)f2bf(acc[r][3]) << 16);
            pv.z = (unsigned int)f2bf(acc[r][4]) | ((unsigned int)f2bf(acc[r][5]) << 16);
            pv.w = (unsigned int)f2bf(acc[r][6]) | ((unsigned int)f2bf(acc[r][7]) << 16);
            *(uint4*)(hq + (size_t)n * 64 + cg * 4) = pv;
        }
        #pragma unroll
        for (int off = 1; off < 8; off <<= 1) {
            pel += __shfl_xor(pel, off, 64);
            per += __shfl_xor(per, off, 64);
        }
        if ((cg & 7) == 0 && n < N_NODES) {
            el[n * 2 + head] = pel;
            er[n * 2 + head] = per;
        }
    }
}

__global__ __launch_bounds__(256) void repr_embed_h(
        const float* __restrict__ emb, const int* __restrict__ Z,
        const float* __restrict__ fc_w, const float* __restrict__ attn_l,
        const float* __restrict__ attn_r,
        float* __restrict__ x, unsigned int* __restrict__ hq,
        float* __restrict__ el, float* __restrict__ er) {
    __shared__ float bufA[TN * XLD];
    int base = blockIdx.x * TN, tid = threadIdx.x;
    int row = tid >> 2;
    int c0 = (tid & 3) << 4;
    int n = base + row;
    int z = (n < N_NODES) ? Z[n] : 0;
    const float* ep = emb + (size_t)z * D_DIM + c0;
    float* bp = bufA + row * XLD + c0;
    #pragma unroll
    for (int j = 0; j < 4; j++) {
        float4 v = *(const float4*)(ep + j * 4);
        *(float4*)(bp + j * 4) = v;
        if (n < N_NODES) *(float4*)(x + (size_t)n * D_DIM + c0 + j * 4) = v;
    }
    __syncthreads();
    gemm_h(base, tid, bufA, fc_w, attn_l, attn_r, hq, el, er);
}

__global__ __launch_bounds__(256) void repr_mlp_h(
        const float* __restrict__ agg, const float* __restrict__ denom,
        const float* __restrict__ w1, const float* __restrict__ b1,
        const float* __restrict__ w2, const float* __restrict__ b2,
        const float* __restrict__ fc_w, const float* __restrict__ attn_l,
        const float* __restrict__ attn_r,
        float* __restrict__ x, unsigned int* __restrict__ hq,
        float* __restrict__ el, float* __restrict__ er) {
    __shared__ float bufA[TN * TLD];
    __shared__ float v1s[TN * XLD];
    int base = blockIdx.x * TN, tid = threadIdx.x;
    load_ssp_agg(base, tid, agg, denom, bufA);
    __syncthreads();
    gemm_mlp(base, tid, w1, b1, w2, b2, x, bufA, v1s);
    gemm_h(base, tid, bufA, fc_w, attn_l, attn_r, hq, el, er);
}

__global__ __launch_bounds__(256) void repr_mlp_out(
        const float* __restrict__ agg, const float* __restrict__ denom,
        const float* __restrict__ w1, const float* __restrict__ b1,
        const float* __restrict__ w2, const float* __restrict__ b2,
        const float* __restrict__ ow1, const float* __restrict__ ob1,
        const float* __restrict__ ow2, const float* __restrict__ ob2,
        float* __restrict__ x, float* __restrict__ hh) {
    __shared__ float bufA[TN * TLD];
    __shared__ float v1s[TN * XLD];
    int base = blockIdx.x * TN, tid = threadIdx.x;
    load_ssp_agg(base, tid, agg, denom, bufA);
    __syncthreads();
    gemm_mlp(base, tid, w1, b1, w2, b2, x, bufA, v1s);
    const int rg = tid >> 4, cg = tid & 15;
    const int r0 = rg * 4, c0 = cg * 8;
    float acc[4][8];
    #pragma unroll
    for (int r = 0; r < 4; r++)
        #pragma unroll
        for (int c = 0; c < 8; c++) acc[r][c] = 0.f;
    for (int k0 = 0; k0 < 64; k0 += 4) {
        float av[4][4];
        #pragma unroll
        for (int r = 0; r < 4; r++)
            *(float4*)av[r] = *(const float4*)&bufA[(r0 + r) * XLD + k0];
        #pragma unroll
        for (int kk = 0; kk < 4; kk++) {
            float4 w0 = *(const float4*)(ow1 + (k0 + kk) * 128 + c0);
            float4 w1v = *(const float4*)(ow1 + (k0 + kk) * 128 + c0 + 4);
            float wf[8] = {w0.x, w0.y, w0.z, w0.w, w1v.x, w1v.y, w1v.z, w1v.w};
            #pragma unroll
            for (int r = 0; r < 4; r++)
                #pragma unroll
                for (int c = 0; c < 8; c++)
                    acc[r][c] = fmaf(av[r][kk], wf[c], acc[r][c]);
        }
    }
    float o1[8], w2c[8];
    #pragma unroll
    for (int c = 0; c < 8; c++) { o1[c] = ob1[c0 + c]; w2c[c] = ow2[c0 + c]; }
    #pragma unroll
    for (int r = 0; r < 4; r++) {
        int n = base + r0 + r;
        float s = 0.f;
        #pragma unroll
        for (int c = 0; c < 8; c++)
            s = fmaf(sspf(acc[r][c] + o1[c]), w2c[c], s);
        #pragma unroll
        for (int off = 1; off < 16; off <<= 1)
            s += __shfl_xor(s, off, 64);
        if (cg == 0 && n < N_NODES) hh[n] = s + ob2[0];
    }
}

// ------------- node-owned LUT message, branchless LDS-atomic accumulate ----------
// Block owns DN=16 consecutive dst nodes (contiguous edge range of the sorted
// list). Per chunk of <=256 edges: (1) each thread stages one edge's metadata
// into LDS (ONE exp pair per edge) and adds denom via LDS atomics; (2) 64
// col-pair lanes x 4 edge-slices walk staged edges with a BRANCHLESS inner loop
// (LDS-broadcast metadata, 2 coalesced gathers, ds_add_f32 into lagg[dd]) so
// the compiler software-pipelines the gathers; (3) coalesced plain stores of
// agg[16][128] + denom. No global atomics; agg written exactly once.
#define DN 16
#define ECHUNK 256
__global__ __launch_bounds__(256) void repr_msg_node(
    const int2* __restrict__ surv, const int* __restrict__ rowptr,
    const float* __restrict__ el, const float* __restrict__ er,
    const unsigned int* __restrict__ hq,
    const unsigned int* __restrict__ lut,
    float* __restrict__ agg, float* __restrict__ denom)
{
    __shared__ float lagg[DN][HD];        // 8 KB
    __shared__ float lden[DN][2];
    __shared__ float ler[DN][2];
    __shared__ float4 sef[ECHUNK];        // {e0, e1, fr, bits(sn*64 | dd<<27)} 4 KB
    __shared__ unsigned int si[ECHUNK];   // i0*64 (lut row offset in uint2 units) 1 KB
    int tid = threadIdx.x;
    int d0 = blockIdx.x * DN;
    int dmax = (N_NODES - d0 < DN) ? (N_NODES - d0) : DN;

    for (int k = tid; k < DN * HD / 4; k += 256)
        ((float4*)lagg)[k] = make_float4(0.f, 0.f, 0.f, 0.f);
    if (tid < DN * 2) {
        ((float*)lden)[tid] = 0.f;
        int d = d0 + (tid >> 1);
        ((float*)ler)[tid] = (d < N_NODES) ? er[2 * d + (tid & 1)] : 0.f;
    }
    __syncthreads();

    int rs0 = rowptr[d0];
    int re0 = rowptr[d0 + dmax];
    const int cp = tid & 63, slice = tid >> 6;
    const uint2* __restrict__ l2p = (const uint2*)lut;

    for (int base = rs0; base < re0; base += ECHUNK) {
        int nc = re0 - base; if (nc > ECHUNK) nc = ECHUNK;
        // ---- stage (one exp pair per edge; each thread <=1 edge) ----
        if (tid < nc) {
            int2 ev = surv[base + tid];
            int sn = (int)((unsigned)ev.x & 0xFFFFu);
            int dd = (int)((unsigned)ev.x >> 16) - d0;
            unsigned rf = (unsigned)ev.y;
            float fr = (float)(rf & 0xFFFFu) * (1.f / 65536.f);
            float2 a = *(const float2*)&el[2 * sn];
            float v0 = a.x + ler[dd][0]; v0 = v0 >= 0.f ? v0 : 0.2f * v0;
            float v1 = a.y + ler[dd][1]; v1 = v1 >= 0.f ? v1 : 0.2f * v1;
            float e0 = __expf(v0), e1 = __expf(v1);
            unsigned pb = (unsigned)(sn * 64) | ((unsigned)dd << 27);
            sef[tid] = make_float4(e0, e1, fr, __uint_as_float(pb));
            si[tid] = (rf >> 16) * 64u;
            atomicAdd(&lden[dd][0], e0);
            atomicAdd(&lden[dd][1], e1);
        }
        __syncthreads();
        // ---- branchless accumulate: contiguous quarter per slice ----
        int jlo = (nc * slice) >> 2;
        int jhi = (nc * (slice + 1)) >> 2;
        #pragma unroll 4
        for (int j = jlo; j < jhi; j++) {
            float4 sv = sef[j];                     // LDS broadcast
            unsigned lo = si[j];
            unsigned pb = __float_as_uint(sv.w);
            uint2 tv = l2p[(size_t)lo + cp];        // 512B coalesced per wave
            unsigned hv = hq[(size_t)(pb & 0x7FFFFFFu) + cp];  // 256B coalesced
            int dd = (int)(pb >> 27);
            float fr = sv.z;
            float s = (cp < 32) ? sv.x : sv.y;      // head0 cols 0-63, head1 64-127
            float wa0 = __uint_as_float(tv.x << 16);
            float wa1 = __uint_as_float(tv.x & 0xFFFF0000u);
            float wb0 = __uint_as_float(tv.y << 16);
            float wb1 = __uint_as_float(tv.y & 0xFFFF0000u);
            float ha = __uint_as_float(hv << 16);
            float hb = __uint_as_float(hv & 0xFFFF0000u);
            float wa = fmaf(fr, wa1 - wa0, wa0);
            float wb = fmaf(fr, wb1 - wb0, wb0);
            atomicAdd(&lagg[dd][2 * cp],     wa * ha * s);   // ds_add_f32
            atomicAdd(&lagg[dd][2 * cp + 1], wb * hb * s);
        }
        __syncthreads();   // protect sef/si reuse + lagg completeness
    }
    // ---- coalesced write-out ----
    for (int k = tid; k < dmax * (HD / 4); k += 256) {
        int node = k >> 5, c4 = (k & 31) * 4;
        *(float4*)&agg[(size_t)(d0 + node) * HD + c4] = *(float4*)&lagg[node][c4];
    }
    if (tid < dmax * 2) denom[2 * d0 + tid] = ((float*)lden)[tid];
}

// ------------- graph segment-sum with LDS privatization -> d_out directly -------------
__global__ void repr_gsum(const float* __restrict__ hh, const int* __restrict__ gids,
                          float* __restrict__ dout) {
    __shared__ float bins[B_GRAPHS];
    int t = threadIdx.x;
    if (t < B_GRAPHS) bins[t] = 0.f;
    __syncthreads();
    int i = blockIdx.x * 256 + t;
    if (i < N_NODES) atomicAdd(&bins[gids[i]], hh[i]);
    __syncthreads();
    if (t < B_GRAPHS && bins[t] != 0.f) atomicAdd(&dout[t], bins[t]);
}

extern "C" void kernel_launch(void* const* d_in, const int* in_sizes, int n_in,
                              void* d_out, int out_size, void* d_ws, size_t ws_size,
                              hipStream_t stream) {
    (void)in_sizes; (void)n_in; (void)out_size; (void)ws_size;
    const float* R      = (const float*)d_in[0];
    const int*   Z      = (const int*)d_in[1];
    const int*   src    = (const int*)d_in[2];
    const int*   dst    = (const int*)d_in[3];
    const int*   gids   = (const int*)d_in[4];
    const float* emb    = (const float*)d_in[5];
    const float* offs   = (const float*)d_in[6];
    const float* widths = (const float*)d_in[7];
    const float* fc_w   = (const float*)d_in[8];
    const float* attn_l = (const float*)d_in[9];
    const float* attn_r = (const float*)d_in[10];
    const float* fw1    = (const float*)d_in[11];
    const float* fb1    = (const float*)d_in[12];
    const float* fw2    = (const float*)d_in[13];
    const float* fb2    = (const float*)d_in[14];
    const float* mw1    = (const float*)d_in[15];
    const float* mb1    = (const float*)d_in[16];
    const float* mw2    = (const float*)d_in[17];
    const float* mb2    = (const float*)d_in[18];
    const float* ow1    = (const float*)d_in[19];
    const float* ob1    = (const float*)d_in[20];
    const float* ow2    = (const float*)d_in[21];
    const float* ob2    = (const float*)d_in[22];

    char* p = (char*)d_ws;
    float* x      = (float*)p; p += (size_t)N_NODES * 64 * 4;
    unsigned int* hq = (unsigned int*)p; p += (size_t)N_NODES * 64 * 4;  // packed bf16 pairs
    float* el     = (float*)p; p += (size_t)N_NODES * 2 * 4;
    float* er     = (float*)p; p += (size_t)N_NODES * 2 * 4;
    float* denom  = (float*)p; p += (size_t)N_NODES * 2 * 4;
    float* agg    = (float*)p; p += (size_t)N_NODES * 128 * 4;
    int2*  surv   = (int2*)p;  p += (size_t)N_EDGES * 8;
    int2*  pk     = (int2*)p;  p += (size_t)N_EDGES * 8;
    int*   rowptr = (int*)p;   p += (size_t)(N_NODES + 1) * 4;
    float* hh     = (float*)p; p += (size_t)N_NODES * 4;
    int*   bsum   = (int*)p;   p += 1024;
    int*   bpref  = (int*)p;   p += 1024;
    // filter-net LUT aliases pk: 3*2049*128*4 = 3,147,264 B <= 6,400,000 B.
    // pk is dead after repr_scatter; lut is built strictly after it.
    unsigned int* lut = (unsigned int*)pk;
    // scan temporaries aliased into x (x written by repr_embed_h, strictly after
    // repr_scatter in stream order):
    int* count = (int*)x;
    int* excl  = (int*)((char*)x + 256 * 1024);
    int* cur   = (int*)((char*)x + 512 * 1024);

    // one-time prep: zero edge counter + d_out
    repr_prep<<<(N_NODES + B_GRAPHS + 255) / 256, 256, 0, stream>>>(
        count, (float*)d_out);
    repr_hist<<<N_EDGES / 256, 256, 0, stream>>>(R, src, dst, count, pk);
    repr_scanA<<<NCHUNK, 256, 0, stream>>>(count, excl, bsum);
    repr_scanB<<<1, 256, 0, stream>>>(bsum, bpref);
    repr_scanC<<<NCHUNK, 256, 0, stream>>>(excl, bpref, cur, rowptr);
    repr_scatter<<<N_EDGES / 256, 256, 0, stream>>>(pk, cur, surv);

    // build the w(r)*C(r) tables (pk is dead from here on)
    repr_lut_build<<<L_LAYERS * (LUT_T / LROWS), 256, 0, stream>>>(
        offs, widths, fw1, fb1, fw2, fb2, lut);

    repr_embed_h<<<NBLK, 256, 0, stream>>>(
        emb, Z, fc_w, attn_l, attn_r, x, hq, el, er);

    for (int l = 0; l < L_LAYERS; l++) {
        repr_msg_node<<<(N_NODES + DN - 1) / DN, 256, 0, stream>>>(
            surv, rowptr, el, er, hq, lut + (size_t)l * LUT_ROWS * HD, agg, denom);
        if (l < L_LAYERS - 1) {
            repr_mlp_h<<<NBLK, 256, 0, stream>>>(
                agg, denom, mw1 + (size_t)l * 128 * 64, mb1 + l * 64,
                mw2 + (size_t)l * 64 * 64, mb2 + l * 64,
                fc_w + (size_t)(l + 1) * 64 * 128, attn_l + (l + 1) * 128,
                attn_r + (l + 1) * 128, x, hq, el, er);
        } else {
            repr_mlp_out<<<NBLK, 256, 0, stream>>>(
                agg, denom, mw1 + (size_t)l * 128 * 64, mb1 + l * 64,
                mw2 + (size_t)l * 64 * 64, mb2 + l * 64,
                ow1, ob1, ow2, ob2, x, hh);
        }
    }
    repr_gsum<<<NCHUNK, 256, 0, stream>>>(hh, gids, (float*)d_out);
}

// Round 10
// 687.559 us; speedup vs baseline: 3.0799x; 3.0799x over previous
//
#include <hip/hip_runtime.h>
#include <stdint.h>

#define N_NODES 50000
#define N_EDGES 800000
#define B_GRAPHS 64
#define D_DIM 64
#define HD 128
#define G_GAUSS 50
#define HID_DIM 128
#define L_LAYERS 3
#define LN2 0.69314718055994530942f
#define PI_OVER_8 0.39269908169872414f
#define NCHUNK 196            // ceil(50000/256)

#define TN 64                 // nodes per node-GEMM block
#define TLD 132               // fp32 LDS leading dim for 128-wide tiles
#define XLD 68                // fp32 LDS leading dim for 64-wide tiles
#define NBLK ((N_NODES + TN - 1) / TN)   // 782

// filter-net lookup table: w(r)*C(r) over r in [0,8), linear interpolation.
// Rows 0..LUT_T-1 cover [0,8); row LUT_T is all-zero (r>=8 cutoff folded in).
#define LUT_T 2048
#define LUT_ROWS (LUT_T + 1)
#define LROWS 8               // table rows built per block

__device__ __forceinline__ float sspf(float x) {
    float ax = fabsf(x);
    return fmaxf(x, 0.f) + __logf(1.f + __expf(-ax)) - LN2;
}
__device__ __forceinline__ unsigned short f2bf(float f) {
    union { float f; unsigned int i; } v; v.f = f;
    unsigned int u = v.i;
    return (unsigned short)((u + 0x7FFFu + ((u >> 16) & 1u)) >> 16);
}

// ------------- one-time: zero edge counter + output -------------
__global__ void repr_prep(int* __restrict__ count, float* __restrict__ dout) {
    int i = blockIdx.x * 256 + threadIdx.x;
    if (i < N_NODES) count[i] = 0;
    else if (i < N_NODES + B_GRAPHS) dout[i - N_NODES] = 0.f;
}

// ------------- one-time: build wc(r) = (ssp(gs@W1+b1)@W2 + b2) * C(r) table -------------
// interleaved bf16: lut[l][i][c] = bf16(wc[i][c]) | bf16(wc[i+1][c])<<16
__global__ __launch_bounds__(256) void repr_lut_build(
    const float* __restrict__ offs, const float* __restrict__ widths,
    const float* __restrict__ fw1, const float* __restrict__ fb1,
    const float* __restrict__ fw2, const float* __restrict__ fb2,
    unsigned int* __restrict__ lut)
{
    __shared__ float gs_s[LROWS + 1][G_GAUSS];
    __shared__ float hid_s[LROWS + 1][HID_DIM];
    __shared__ float wc_s[LROWS + 1][HD];
    const int nb = LUT_T / LROWS;            // 256 blocks per layer
    int l = blockIdx.x / nb;
    int i0r = (blockIdx.x % nb) * LROWS;
    int tid = threadIdx.x;
    const float step = 8.0f / LUT_T;

    for (int j = tid; j < (LROWS + 1) * G_GAUSS; j += 256) {
        int r = j / G_GAUSS, k = j - r * G_GAUSS;
        float rr = (i0r + r) * step;
        float wdt = widths[k];
        float dr = rr - offs[k];
        gs_s[r][k] = expf(-0.5f / (wdt * wdt) * dr * dr);
    }
    __syncthreads();

    int c = tid & 127, sub = tid >> 7;
    int rlo = sub * 4;                       // rows 0..4 / 4..8 (row 4 dup, benign)
    {
        const float* W1 = fw1 + (size_t)l * G_GAUSS * HID_DIM + c;
        float acc[5];
        float bb = fb1[l * HID_DIM + c];
        #pragma unroll
        for (int r = 0; r < 5; r++) acc[r] = bb;
        for (int k = 0; k < G_GAUSS; k++) {
            float wv = W1[k * HID_DIM];
            #pragma unroll
            for (int r = 0; r < 5; r++)
                acc[r] = fmaf(gs_s[rlo + r][k], wv, acc[r]);
        }
        #pragma unroll
        for (int r = 0; r < 5; r++) hid_s[rlo + r][c] = sspf(acc[r]);
    }
    __syncthreads();
    {
        const float* W2 = fw2 + (size_t)l * HID_DIM * HD + c;
        float acc[5];
        float bb = fb2[l * HD + c];
        #pragma unroll
        for (int r = 0; r < 5; r++) acc[r] = bb;
        for (int k = 0; k < HID_DIM; k++) {
            float wv = W2[k * HD];
            #pragma unroll
            for (int r = 0; r < 5; r++)
                acc[r] = fmaf(hid_s[rlo + r][k], wv, acc[r]);
        }
        #pragma unroll
        for (int r = 0; r < 5; r++) {
            float rr = (i0r + rlo + r) * step;
            float C = (rr < 8.0f) ? 0.5f * (cosf(rr * PI_OVER_8) + 1.f) : 0.f;
            wc_s[rlo + r][c] = acc[r] * C;
        }
    }
    __syncthreads();
    for (int j = tid; j < LROWS * HD; j += 256) {
        int r = j >> 7, cc = j & 127;
        unsigned int lo = f2bf(wc_s[r][cc]);
        unsigned int hi = f2bf(wc_s[r + 1][cc]);
        lut[((size_t)l * LUT_ROWS + i0r + r) * HD + cc] = lo | (hi << 16);
    }
    // last block of each layer writes the zeros row (r >= 8 cutoff)
    if (i0r == LUT_T - LROWS && tid < HD)
        lut[((size_t)l * LUT_ROWS + LUT_T) * HD + tid] = 0u;
}

// ------------- histogram + pack {src|dst<<16, r fixed-point} per edge -------------
__global__ void repr_hist(const float* __restrict__ R,
                          const int* __restrict__ src, const int* __restrict__ dst,
                          int* __restrict__ count,
                          int2* __restrict__ pk) {
    int e = blockIdx.x * blockDim.x + threadIdx.x;
    if (e >= N_EDGES) return;
    int s = src[e], d = dst[e];
    float dx = R[3*s+0] - R[3*d+0];
    float dy = R[3*s+1] - R[3*d+1];
    float dz = R[3*s+2] - R[3*d+2];
    float r = sqrtf(dx*dx + dy*dy + dz*dz);
    // r*2^24; i0 = rf>>16 in [0,2047] for r<8, else 2048 -> zeros row
    unsigned rf = (r < 8.0f) ? (unsigned)(r * 16777216.f) : (2048u << 16);
    if (rf > (2048u << 16)) rf = 2048u << 16;
    pk[e] = make_int2((int)((unsigned)s | ((unsigned)d << 16)), (int)rf);
    atomicAdd(&count[d], 1);
}

// ------------- 2-level exclusive scan over 50000 counts -------------
__global__ void repr_scanA(const int* __restrict__ cnt, int* __restrict__ excl,
                           int* __restrict__ bsum) {
    __shared__ int tmp[256];
    int t = threadIdx.x, b = blockIdx.x;
    int i = b * 256 + t;
    int v = (i < N_NODES) ? cnt[i] : 0;
    tmp[t] = v; __syncthreads();
    for (int off = 1; off < 256; off <<= 1) {
        int add = (t >= off) ? tmp[t - off] : 0;
        __syncthreads();
        tmp[t] += add;
        __syncthreads();
    }
    if (i < N_NODES) excl[i] = tmp[t] - v;
    if (t == 255) bsum[b] = tmp[255];
}
__global__ void repr_scanB(const int* __restrict__ bsum, int* __restrict__ bpref) {
    __shared__ int tmp[256];
    int t = threadIdx.x;
    int v = (t < NCHUNK) ? bsum[t] : 0;
    tmp[t] = v; __syncthreads();
    for (int off = 1; off < 256; off <<= 1) {
        int add = (t >= off) ? tmp[t - off] : 0;
        __syncthreads();
        tmp[t] += add;
        __syncthreads();
    }
    if (t < NCHUNK) bpref[t] = tmp[t] - v;
}
__global__ void repr_scanC(const int* __restrict__ excl, const int* __restrict__ bpref,
                           int* __restrict__ cur, int* __restrict__ rowptr) {
    int i = blockIdx.x * 256 + threadIdx.x;
    if (i < N_NODES) { int v = excl[i] + bpref[blockIdx.x]; cur[i] = v; rowptr[i] = v; }
    if (i == 0) rowptr[N_NODES] = N_EDGES;
}

// ------------- scatter: dst-sorted packed edge list, one 8B store per edge -------------
__global__ void repr_scatter(const int2* __restrict__ pk,
                             int* __restrict__ cur,
                             int2* __restrict__ surv) {
    int e = blockIdx.x * blockDim.x + threadIdx.x;
    if (e >= N_EDGES) return;
    int2 v = pk[e];
    int d = (int)((unsigned)v.x >> 16);
    int pos = atomicAdd(&cur[d], 1);
    surv[pos] = v;
}

// ================= tiled fp32 node GEMMs (64 nodes / block, 256 threads) =================

__device__ __forceinline__ void load_ssp_agg(int base, int tid,
        const float* __restrict__ agg, float* __restrict__ bufA) {
    int row = tid >> 2;
    int c0 = (tid & 3) << 5;
    const float* ap = agg + (size_t)(base + row) * HD + c0;
    float* tp = bufA + row * TLD + c0;
    #pragma unroll
    for (int j = 0; j < 8; j++) {
        float4 v = *(const float4*)(ap + j * 4);
        tp[j*4+0] = sspf(v.x); tp[j*4+1] = sspf(v.y);
        tp[j*4+2] = sspf(v.z); tp[j*4+3] = sspf(v.w);
    }
}

__device__ __forceinline__ void gemm_mlp(int base, int tid,
        const float* __restrict__ w1, const float* __restrict__ b1,
        const float* __restrict__ w2, const float* __restrict__ b2,
        float* __restrict__ x, float* __restrict__ bufA, float* __restrict__ v1s)
{
    const int rg = tid >> 4, cg = tid & 15;
    const int r0 = rg * 4, c0 = cg * 4;
    float acc[4][4];
    #pragma unroll
    for (int r = 0; r < 4; r++)
        #pragma unroll
        for (int c = 0; c < 4; c++) acc[r][c] = 0.f;
    for (int k0 = 0; k0 < 128; k0 += 4) {
        float av[4][4];
        #pragma unroll
        for (int r = 0; r < 4; r++)
            *(float4*)av[r] = *(const float4*)&bufA[(r0 + r) * TLD + k0];
        #pragma unroll
        for (int kk = 0; kk < 4; kk++) {
            float4 wv = *(const float4*)(w1 + (k0 + kk) * 64 + c0);
            float wf[4] = {wv.x, wv.y, wv.z, wv.w};
            #pragma unroll
            for (int r = 0; r < 4; r++)
                #pragma unroll
                for (int c = 0; c < 4; c++)
                    acc[r][c] = fmaf(av[r][kk], wf[c], acc[r][c]);
        }
    }
    {
        float4 bv = *(const float4*)(b1 + c0);
        float ba[4] = {bv.x, bv.y, bv.z, bv.w};
        #pragma unroll
        for (int r = 0; r < 4; r++)
            #pragma unroll
            for (int c = 0; c < 4; c++)
                v1s[(r0 + r) * XLD + c0 + c] = sspf(acc[r][c] + ba[c]);
    }
    __syncthreads();
    float acc2[4][4];
    #pragma unroll
    for (int r = 0; r < 4; r++)
        #pragma unroll
        for (int c = 0; c < 4; c++) acc2[r][c] = 0.f;
    for (int k0 = 0; k0 < 64; k0 += 4) {
        float av[4][4];
        #pragma unroll
        for (int r = 0; r < 4; r++)
            *(float4*)av[r] = *(const float4*)&v1s[(r0 + r) * XLD + k0];
        #pragma unroll
        for (int kk = 0; kk < 4; kk++) {
            float4 wv = *(const float4*)(w2 + (k0 + kk) * 64 + c0);
            float wf[4] = {wv.x, wv.y, wv.z, wv.w};
            #pragma unroll
            for (int r = 0; r < 4; r++)
                #pragma unroll
                for (int c = 0; c < 4; c++)
                    acc2[r][c] = fmaf(av[r][kk], wf[c], acc2[r][c]);
        }
    }
    {
        float4 bv = *(const float4*)(b2 + c0);
        #pragma unroll
        for (int r = 0; r < 4; r++) {
            int n = base + r0 + r;
            float4 xv = *(const float4*)(x + (size_t)n * 64 + c0);
            float4 o;
            o.x = acc2[r][0] + bv.x + xv.x;
            o.y = acc2[r][1] + bv.y + xv.y;
            o.z = acc2[r][2] + bv.z + xv.z;
            o.w = acc2[r][3] + bv.w + xv.w;
            *(float4*)&bufA[(r0 + r) * XLD + c0] = o;
            if (n < N_NODES) *(float4*)(x + (size_t)n * 64 + c0) = o;
        }
    }
    __syncthreads();
}

// h stored packed bf16: hq[n*64 + c/2] = bf16(h[c]) | bf16(h[c+1])<<16
__device__ __forceinline__ void gemm_h(int base, int tid,
        const float* __restrict__ bufA,
        const float* __restrict__ fc_w, const float* __restrict__ attn_l,
        const float* __restrict__ attn_r,
        unsigned int* __restrict__ hq, float* __restrict__ el, float* __restrict__ er)
{
    const int rg = tid >> 4, cg = tid & 15;
    const int r0 = rg * 4, c0 = cg * 8;
    float acc[4][8];
    #pragma unroll
    for (int r = 0; r < 4; r++)
        #pragma unroll
        for (int c = 0; c < 8; c++) acc[r][c] = 0.f;
    for (int k0 = 0; k0 < 64; k0 += 4) {
        float av[4][4];
        #pragma unroll
        for (int r = 0; r < 4; r++)
            *(float4*)av[r] = *(const float4*)&bufA[(r0 + r) * XLD + k0];
        #pragma unroll
        for (int kk = 0; kk < 4; kk++) {
            float4 w0 = *(const float4*)(fc_w + (k0 + kk) * 128 + c0);
            float4 w1v = *(const float4*)(fc_w + (k0 + kk) * 128 + c0 + 4);
            float wf[8] = {w0.x, w0.y, w0.z, w0.w, w1v.x, w1v.y, w1v.z, w1v.w};
            #pragma unroll
            for (int r = 0; r < 4; r++)
                #pragma unroll
                for (int c = 0; c < 8; c++)
                    acc[r][c] = fmaf(av[r][kk], wf[c], acc[r][c]);
        }
    }
    float al[8], ar[8];
    #pragma unroll
    for (int c = 0; c < 8; c++) { al[c] = attn_l[c0 + c]; ar[c] = attn_r[c0 + c]; }
    int head = cg >> 3;
    #pragma unroll
    for (int r = 0; r < 4; r++) {
        int n = base + r0 + r;
        float pel = 0.f, per = 0.f;
        #pragma unroll
        for (int c = 0; c < 8; c++) {
            pel = fmaf(acc[r][c], al[c], pel);
            per = fmaf(acc[r][c], ar[c], per);
        }
        if (n < N_NODES) {
            uint4 pv;
            pv.x = (unsigned int)f2bf(acc[r][0]) | ((unsigned int)f2bf(acc[r][1]) << 16);
            pv.y = (unsigned int)f2bf(acc[r][2]) | ((unsigned int)f2bf(acc[r][3]) << 16);
            pv.z = (unsigned int)f2bf(acc[r][4]) | ((unsigned int)f2bf(acc[r][5]) << 16);
            pv.w = (unsigned int)f2bf(acc[r][6]) | ((unsigned int)f2bf(acc[r][7]) << 16);
            *(uint4*)(hq + (size_t)n * 64 + cg * 4) = pv;
        }
        #pragma unroll
        for (int off = 1; off < 8; off <<= 1) {
            pel += __shfl_xor(pel, off, 64);
            per += __shfl_xor(per, off, 64);
        }
        if ((cg & 7) == 0 && n < N_NODES) {
            el[n * 2 + head] = pel;
            er[n * 2 + head] = per;
        }
    }
}

__global__ __launch_bounds__(256) void repr_embed_h(
        const float* __restrict__ emb, const int* __restrict__ Z,
        const float* __restrict__ fc_w, const float* __restrict__ attn_l,
        const float* __restrict__ attn_r,
        float* __restrict__ x, unsigned int* __restrict__ hq,
        float* __restrict__ el, float* __restrict__ er) {
    __shared__ float bufA[TN * XLD];
    int base = blockIdx.x * TN, tid = threadIdx.x;
    int row = tid >> 2;
    int c0 = (tid & 3) << 4;
    int n = base + row;
    int z = (n < N_NODES) ? Z[n] : 0;
    const float* ep = emb + (size_t)z * D_DIM + c0;
    float* bp = bufA + row * XLD + c0;
    #pragma unroll
    for (int j = 0; j < 4; j++) {
        float4 v = *(const float4*)(ep + j * 4);
        *(float4*)(bp + j * 4) = v;
        if (n < N_NODES) *(float4*)(x + (size_t)n * D_DIM + c0 + j * 4) = v;
    }
    __syncthreads();
    gemm_h(base, tid, bufA, fc_w, attn_l, attn_r, hq, el, er);
}

__global__ __launch_bounds__(256) void repr_mlp_h(
        const float* __restrict__ agg,
        const float* __restrict__ w1, const float* __restrict__ b1,
        const float* __restrict__ w2, const float* __restrict__ b2,
        const float* __restrict__ fc_w, const float* __restrict__ attn_l,
        const float* __restrict__ attn_r,
        float* __restrict__ x, unsigned int* __restrict__ hq,
        float* __restrict__ el, float* __restrict__ er) {
    __shared__ float bufA[TN * TLD];
    __shared__ float v1s[TN * XLD];
    int base = blockIdx.x * TN, tid = threadIdx.x;
    load_ssp_agg(base, tid, agg, bufA);
    __syncthreads();
    gemm_mlp(base, tid, w1, b1, w2, b2, x, bufA, v1s);
    gemm_h(base, tid, bufA, fc_w, attn_l, attn_r, hq, el, er);
}

__global__ __launch_bounds__(256) void repr_mlp_out(
        const float* __restrict__ agg,
        const float* __restrict__ w1, const float* __restrict__ b1,
        const float* __restrict__ w2, const float* __restrict__ b2,
        const float* __restrict__ ow1, const float* __restrict__ ob1,
        const float* __restrict__ ow2, const float* __restrict__ ob2,
        float* __restrict__ x, float* __restrict__ hh) {
    __shared__ float bufA[TN * TLD];
    __shared__ float v1s[TN * XLD];
    int base = blockIdx.x * TN, tid = threadIdx.x;
    load_ssp_agg(base, tid, agg, bufA);
    __syncthreads();
    gemm_mlp(base, tid, w1, b1, w2, b2, x, bufA, v1s);
    const int rg = tid >> 4, cg = tid & 15;
    const int r0 = rg * 4, c0 = cg * 8;
    float acc[4][8];
    #pragma unroll
    for (int r = 0; r < 4; r++)
        #pragma unroll
        for (int c = 0; c < 8; c++) acc[r][c] = 0.f;
    for (int k0 = 0; k0 < 64; k0 += 4) {
        float av[4][4];
        #pragma unroll
        for (int r = 0; r < 4; r++)
            *(float4*)av[r] = *(const float4*)&bufA[(r0 + r) * XLD + k0];
        #pragma unroll
        for (int kk = 0; kk < 4; kk++) {
            float4 w0 = *(const float4*)(ow1 + (k0 + kk) * 128 + c0);
            float4 w1v = *(const float4*)(ow1 + (k0 + kk) * 128 + c0 + 4);
            float wf[8] = {w0.x, w0.y, w0.z, w0.w, w1v.x, w1v.y, w1v.z, w1v.w};
            #pragma unroll
            for (int r = 0; r < 4; r++)
                #pragma unroll
                for (int c = 0; c < 8; c++)
                    acc[r][c] = fmaf(av[r][kk], wf[c], acc[r][c]);
        }
    }
    float o1[8], w2c[8];
    #pragma unroll
    for (int c = 0; c < 8; c++) { o1[c] = ob1[c0 + c]; w2c[c] = ow2[c0 + c]; }
    #pragma unroll
    for (int r = 0; r < 4; r++) {
        int n = base + r0 + r;
        float s = 0.f;
        #pragma unroll
        for (int c = 0; c < 8; c++)
            s = fmaf(sspf(acc[r][c] + o1[c]), w2c[c], s);
        #pragma unroll
        for (int off = 1; off < 16; off <<= 1)
            s += __shfl_xor(s, off, 64);
        if (cg == 0 && n < N_NODES) hh[n] = s + ob2[0];
    }
}

// ------------- softmax denominators (all edges, sorted list) + agg zeroing -------------
__global__ void repr_alpha(const int2* __restrict__ surv, const int* __restrict__ rowptr,
                           const float* __restrict__ el, const float* __restrict__ er,
                           float2* __restrict__ md, float* __restrict__ agg) {
    int t = blockIdx.x * 256 + threadIdx.x;
    int d = t >> 4;
    int lane16 = t & 15;
    if (d >= N_NODES) return;
    float4 z = make_float4(0.f, 0.f, 0.f, 0.f);
    float4* ar = (float4*)(agg + (size_t)d * HD);
    ar[lane16 * 2] = z;
    ar[lane16 * 2 + 1] = z;
    int rs = rowptr[d];
    int re = rowptr[d + 1];
    float2 erd = *(const float2*)&er[2 * d];
    float s0 = 0.f, s1 = 0.f;
    for (int i = rs + lane16; i < re; i += 16) {
        int s = (int)((unsigned)surv[i].x & 0xFFFFu);
        float2 a = *(const float2*)&el[2 * s];
        float v0 = a.x + erd.x; v0 = v0 >= 0.f ? v0 : 0.2f * v0;
        float v1 = a.y + erd.y; v1 = v1 >= 0.f ? v1 : 0.2f * v1;
        s0 += __expf(v0);
        s1 += __expf(v1);
    }
    #pragma unroll
    for (int off = 8; off > 0; off >>= 1) {
        s0 += __shfl_xor(s0, off, 64);
        s1 += __shfl_xor(s1, off, 64);
    }
    if (lane16 == 0) md[d] = make_float2(1.f / s0, 1.f / s1);
}

// ------------- LUT-based message + segmented-reduce scatter -------------
// Per edge: lerp wc(r) from the interleaved bf16 table (uint2 = 2 cols, both
// lerp rows), multiply by packed-bf16 h[src] and the per-(edge,head) alpha
// scale, accumulate segmented sums in registers. r>=8 edges hit the zeros row.
// 256 threads = 64 col-pairs x 4 row-subranges of 16 edges. 800000/64 tiles.
#define TILE 64
__global__ __launch_bounds__(256) void repr_msg_lut(
    const int2* __restrict__ surv,
    const float* __restrict__ el, const float* __restrict__ er,
    const float2* __restrict__ md, const unsigned int* __restrict__ hq,
    const unsigned int* __restrict__ lut,
    float* __restrict__ agg)
{
    __shared__ int4 rowinfo[TILE];     // {lut row i0, src, dst, frac bits}
    __shared__ float scl[TILE][2];
    int base = blockIdx.x * TILE;
    int tid = threadIdx.x;
    if (tid < TILE) {
        int2 ev = surv[base + tid];
        int sn = (int)((unsigned)ev.x & 0xFFFFu);
        int d  = (int)((unsigned)ev.x >> 16);
        unsigned rf = (unsigned)ev.y;
        int i0 = (int)(rf >> 16);
        float fr = (float)(rf & 0xFFFFu) * (1.f / 65536.f);
        float2 a = *(const float2*)&el[2 * sn];
        float2 b = *(const float2*)&er[2 * d];
        float2 rd = md[d];
        float v0 = a.x + b.x; v0 = v0 >= 0.f ? v0 : 0.2f * v0;
        float v1 = a.y + b.y; v1 = v1 >= 0.f ? v1 : 0.2f * v1;
        float sc0 = __expf(v0) * rd.x;       // C(r) is folded into the table
        float sc1 = __expf(v1) * rd.y;
        rowinfo[tid] = make_int4(i0, sn, d, __float_as_int(fr));
        scl[tid][0] = sc0; scl[tid][1] = sc1;
    }
    __syncthreads();
    const int cp = tid & 63;           // col pair: cols 2cp, 2cp+1
    const int sp = tid >> 6;           // row-subrange: rows [sp*16, sp*16+16)
    const int head = cp >> 5;          // cols 0-63 head0, 64-127 head1
    const int lo = sp * 16;
    const uint2* __restrict__ l2p = (const uint2*)lut;
    float sum0 = 0.f, sum1 = 0.f;
    int cur_d = -1;
    int seg_first = 1;                 // current segment started at subrange begin
    #pragma unroll 4
    for (int j = 0; j < 16; j++) {
        int r = lo + j;
        int4 ri = rowinfo[r];          // wave-uniform LDS broadcast
        if (ri.z != cur_d) {
            if (cur_d >= 0) {
                float* ap = &agg[(size_t)cur_d * HD + 2 * cp];
                // segment possibly extends into previous subrange/block -> atomic
                if (seg_first) { atomicAdd(ap, sum0); atomicAdd(ap + 1, sum1); }
                else *(float2*)ap = make_float2(sum0, sum1);
            }
            cur_d = ri.z; sum0 = 0.f; sum1 = 0.f; seg_first = (j == 0);
        }
        uint2 tv = l2p[(size_t)ri.x * 64 + cp];
        float fr = __int_as_float(ri.w);
        float wa0 = __uint_as_float(tv.x << 16);
        float wa1 = __uint_as_float(tv.x & 0xFFFF0000u);
        float wb0 = __uint_as_float(tv.y << 16);
        float wb1 = __uint_as_float(tv.y & 0xFFFF0000u);
        unsigned int hv = hq[(size_t)ri.y * 64 + cp];
        float ha = __uint_as_float(hv << 16);
        float hb = __uint_as_float(hv & 0xFFFF0000u);
        float s = scl[r][head];
        float wa = fmaf(fr, wa1 - wa0, wa0);
        float wb = fmaf(fr, wb1 - wb0, wb0);
        sum0 = fmaf(wa * ha, s, sum0);
        sum1 = fmaf(wb * hb, s, sum1);
    }
    // trailing segment may continue into next subrange/block -> atomic
    if (cur_d >= 0) {
        float* ap = &agg[(size_t)cur_d * HD + 2 * cp];
        atomicAdd(ap, sum0); atomicAdd(ap + 1, sum1);
    }
}

// ------------- graph segment-sum with LDS privatization -> d_out directly -------------
__global__ void repr_gsum(const float* __restrict__ hh, const int* __restrict__ gids,
                          float* __restrict__ dout) {
    __shared__ float bins[B_GRAPHS];
    int t = threadIdx.x;
    if (t < B_GRAPHS) bins[t] = 0.f;
    __syncthreads();
    int i = blockIdx.x * 256 + t;
    if (i < N_NODES) atomicAdd(&bins[gids[i]], hh[i]);
    __syncthreads();
    if (t < B_GRAPHS && bins[t] != 0.f) atomicAdd(&dout[t], bins[t]);
}

extern "C" void kernel_launch(void* const* d_in, const int* in_sizes, int n_in,
                              void* d_out, int out_size, void* d_ws, size_t ws_size,
                              hipStream_t stream) {
    (void)in_sizes; (void)n_in; (void)out_size; (void)ws_size;
    const float* R      = (const float*)d_in[0];
    const int*   Z      = (const int*)d_in[1];
    const int*   src    = (const int*)d_in[2];
    const int*   dst    = (const int*)d_in[3];
    const int*   gids   = (const int*)d_in[4];
    const float* emb    = (const float*)d_in[5];
    const float* offs   = (const float*)d_in[6];
    const float* widths = (const float*)d_in[7];
    const float* fc_w   = (const float*)d_in[8];
    const float* attn_l = (const float*)d_in[9];
    const float* attn_r = (const float*)d_in[10];
    const float* fw1    = (const float*)d_in[11];
    const float* fb1    = (const float*)d_in[12];
    const float* fw2    = (const float*)d_in[13];
    const float* fb2    = (const float*)d_in[14];
    const float* mw1    = (const float*)d_in[15];
    const float* mb1    = (const float*)d_in[16];
    const float* mw2    = (const float*)d_in[17];
    const float* mb2    = (const float*)d_in[18];
    const float* ow1    = (const float*)d_in[19];
    const float* ob1    = (const float*)d_in[20];
    const float* ow2    = (const float*)d_in[21];
    const float* ob2    = (const float*)d_in[22];

    char* p = (char*)d_ws;
    float* x      = (float*)p; p += (size_t)N_NODES * 64 * 4;
    unsigned int* hq = (unsigned int*)p; p += (size_t)N_NODES * 64 * 4;  // packed bf16 pairs
    float* el     = (float*)p; p += (size_t)N_NODES * 2 * 4;
    float* er     = (float*)p; p += (size_t)N_NODES * 2 * 4;
    float2* md    = (float2*)p; p += (size_t)N_NODES * 8;
    float* agg    = (float*)p; p += (size_t)N_NODES * 128 * 4;
    int2*  surv   = (int2*)p;  p += (size_t)N_EDGES * 8;
    int2*  pk     = (int2*)p;  p += (size_t)N_EDGES * 8;
    int*   rowptr = (int*)p;   p += (size_t)(N_NODES + 1) * 4;
    float* hh     = (float*)p; p += (size_t)N_NODES * 4;
    int*   bsum   = (int*)p;   p += 1024;
    int*   bpref  = (int*)p;   p += 1024;
    // filter-net LUT aliases pk: 3*2049*128*4 = 3,147,264 B <= 6,400,000 B.
    // pk is dead after repr_scatter; lut is built strictly after it.
    unsigned int* lut = (unsigned int*)pk;
    // scan temporaries aliased into x (x written by repr_embed_h, strictly after
    // repr_scatter in stream order):
    int* count = (int*)x;
    int* excl  = (int*)((char*)x + 256 * 1024);
    int* cur   = (int*)((char*)x + 512 * 1024);

    // one-time prep: zero edge counter + d_out
    repr_prep<<<(N_NODES + B_GRAPHS + 255) / 256, 256, 0, stream>>>(
        count, (float*)d_out);
    repr_hist<<<N_EDGES / 256, 256, 0, stream>>>(R, src, dst, count, pk);
    repr_scanA<<<NCHUNK, 256, 0, stream>>>(count, excl, bsum);
    repr_scanB<<<1, 256, 0, stream>>>(bsum, bpref);
    repr_scanC<<<NCHUNK, 256, 0, stream>>>(excl, bpref, cur, rowptr);
    repr_scatter<<<N_EDGES / 256, 256, 0, stream>>>(pk, cur, surv);

    // build the w(r)*C(r) tables (pk is dead from here on)
    repr_lut_build<<<L_LAYERS * (LUT_T / LROWS), 256, 0, stream>>>(
        offs, widths, fw1, fb1, fw2, fb2, lut);

    repr_embed_h<<<NBLK, 256, 0, stream>>>(
        emb, Z, fc_w, attn_l, attn_r, x, hq, el, er);

    for (int l = 0; l < L_LAYERS; l++) {
        repr_alpha<<<(N_NODES * 16 + 255) / 256, 256, 0, stream>>>(
            surv, rowptr, el, er, md, agg);
        repr_msg_lut<<<N_EDGES / TILE, 256, 0, stream>>>(
            surv, el, er, md, hq, lut + (size_t)l * LUT_ROWS * HD, agg);
        if (l < L_LAYERS - 1) {
            repr_mlp_h<<<NBLK, 256, 0, stream>>>(
                agg, mw1 + (size_t)l * 128 * 64, mb1 + l * 64,
                mw2 + (size_t)l * 64 * 64, mb2 + l * 64,
                fc_w + (size_t)(l + 1) * 64 * 128, attn_l + (l + 1) * 128,
                attn_r + (l + 1) * 128, x, hq, el, er);
        } else {
            repr_mlp_out<<<NBLK, 256, 0, stream>>>(
                agg, mw1 + (size_t)l * 128 * 64, mb1 + l * 64,
                mw2 + (size_t)l * 64 * 64, mb2 + l * 64,
                ow1, ob1, ow2, ob2, x, hh);
        }
    }
    repr_gsum<<<NCHUNK, 256, 0, stream>>>(hh, gids, (float*)d_out);
}

// Round 11
// 638.727 us; speedup vs baseline: 3.3154x; 1.0765x over previous
//
#include <hip/hip_runtime.h>
#include <stdint.h>

#define N_NODES 50000
#define N_EDGES 800000
#define B_GRAPHS 64
#define D_DIM 64
#define HD 128
#define G_GAUSS 50
#define HID_DIM 128
#define L_LAYERS 3
#define LN2 0.69314718055994530942f
#define PI_OVER_8 0.39269908169872414f
#define NCHUNK 196            // ceil(50000/256)

#define TN 64                 // nodes per node-GEMM block
#define TLD 132               // fp32 LDS leading dim for 128-wide tiles
#define XLD 68                // fp32 LDS leading dim for 64-wide tiles
#define NBLK ((N_NODES + TN - 1) / TN)   // 782

// filter-net lookup table: w(r)*C(r) over r in [0,8), linear interpolation.
// Rows 0..LUT_T-1 cover [0,8); row LUT_T is all-zero (r>=8 cutoff folded in).
#define LUT_T 2048
#define LUT_ROWS (LUT_T + 1)
#define LROWS 8               // table rows built per block

__device__ __forceinline__ float sspf(float x) {
    float ax = fabsf(x);
    return fmaxf(x, 0.f) + __logf(1.f + __expf(-ax)) - LN2;
}
__device__ __forceinline__ unsigned short f2bf(float f) {
    union { float f; unsigned int i; } v; v.f = f;
    unsigned int u = v.i;
    return (unsigned short)((u + 0x7FFFu + ((u >> 16) & 1u)) >> 16);
}

// ------------- one-time: zero edge counter + output -------------
__global__ void repr_prep(int* __restrict__ count, float* __restrict__ dout) {
    int i = blockIdx.x * 256 + threadIdx.x;
    if (i < N_NODES) count[i] = 0;
    else if (i < N_NODES + B_GRAPHS) dout[i - N_NODES] = 0.f;
}

// ------------- per-layer: zero agg (50000x128) + denom (100000) -------------
#define ZTOT ((N_NODES * HD + 2 * N_NODES) / 4)   // float4 count = 1,625,000
__global__ void repr_zero(float* __restrict__ agg, float* __restrict__ denom) {
    int i = blockIdx.x * 256 + threadIdx.x;
    float4 z = make_float4(0.f, 0.f, 0.f, 0.f);
    if (i < N_NODES * HD / 4) ((float4*)agg)[i] = z;
    else if (i < ZTOT) ((float4*)denom)[i - N_NODES * HD / 4] = z;
}

// ------------- one-time: build wc(r) = (ssp(gs@W1+b1)@W2 + b2) * C(r) table -------------
// interleaved bf16: lut[l][i][c] = bf16(wc[i][c]) | bf16(wc[i+1][c])<<16
__global__ __launch_bounds__(256) void repr_lut_build(
    const float* __restrict__ offs, const float* __restrict__ widths,
    const float* __restrict__ fw1, const float* __restrict__ fb1,
    const float* __restrict__ fw2, const float* __restrict__ fb2,
    unsigned int* __restrict__ lut)
{
    __shared__ float gs_s[LROWS + 1][G_GAUSS];
    __shared__ float hid_s[LROWS + 1][HID_DIM];
    __shared__ float wc_s[LROWS + 1][HD];
    const int nb = LUT_T / LROWS;            // 256 blocks per layer
    int l = blockIdx.x / nb;
    int i0r = (blockIdx.x % nb) * LROWS;
    int tid = threadIdx.x;
    const float step = 8.0f / LUT_T;

    for (int j = tid; j < (LROWS + 1) * G_GAUSS; j += 256) {
        int r = j / G_GAUSS, k = j - r * G_GAUSS;
        float rr = (i0r + r) * step;
        float wdt = widths[k];
        float dr = rr - offs[k];
        gs_s[r][k] = expf(-0.5f / (wdt * wdt) * dr * dr);
    }
    __syncthreads();

    int c = tid & 127, sub = tid >> 7;
    int rlo = sub * 4;                       // rows 0..4 / 4..8 (row 4 dup, benign)
    {
        const float* W1 = fw1 + (size_t)l * G_GAUSS * HID_DIM + c;
        float acc[5];
        float bb = fb1[l * HID_DIM + c];
        #pragma unroll
        for (int r = 0; r < 5; r++) acc[r] = bb;
        for (int k = 0; k < G_GAUSS; k++) {
            float wv = W1[k * HID_DIM];
            #pragma unroll
            for (int r = 0; r < 5; r++)
                acc[r] = fmaf(gs_s[rlo + r][k], wv, acc[r]);
        }
        #pragma unroll
        for (int r = 0; r < 5; r++) hid_s[rlo + r][c] = sspf(acc[r]);
    }
    __syncthreads();
    {
        const float* W2 = fw2 + (size_t)l * HID_DIM * HD + c;
        float acc[5];
        float bb = fb2[l * HD + c];
        #pragma unroll
        for (int r = 0; r < 5; r++) acc[r] = bb;
        for (int k = 0; k < HID_DIM; k++) {
            float wv = W2[k * HD];
            #pragma unroll
            for (int r = 0; r < 5; r++)
                acc[r] = fmaf(hid_s[rlo + r][k], wv, acc[r]);
        }
        #pragma unroll
        for (int r = 0; r < 5; r++) {
            float rr = (i0r + rlo + r) * step;
            float C = (rr < 8.0f) ? 0.5f * (cosf(rr * PI_OVER_8) + 1.f) : 0.f;
            wc_s[rlo + r][c] = acc[r] * C;
        }
    }
    __syncthreads();
    for (int j = tid; j < LROWS * HD; j += 256) {
        int r = j >> 7, cc = j & 127;
        unsigned int lo = f2bf(wc_s[r][cc]);
        unsigned int hi = f2bf(wc_s[r + 1][cc]);
        lut[((size_t)l * LUT_ROWS + i0r + r) * HD + cc] = lo | (hi << 16);
    }
    // last block of each layer writes the zeros row (r >= 8 cutoff)
    if (i0r == LUT_T - LROWS && tid < HD)
        lut[((size_t)l * LUT_ROWS + LUT_T) * HD + tid] = 0u;
}

// ------------- histogram + pack {src|dst<<16, r fixed-point} per edge -------------
__global__ void repr_hist(const float* __restrict__ R,
                          const int* __restrict__ src, const int* __restrict__ dst,
                          int* __restrict__ count,
                          int2* __restrict__ pk) {
    int e = blockIdx.x * blockDim.x + threadIdx.x;
    if (e >= N_EDGES) return;
    int s = src[e], d = dst[e];
    float dx = R[3*s+0] - R[3*d+0];
    float dy = R[3*s+1] - R[3*d+1];
    float dz = R[3*s+2] - R[3*d+2];
    float r = sqrtf(dx*dx + dy*dy + dz*dz);
    // r*2^24; i0 = rf>>16 in [0,2047] for r<8, else 2048 -> zeros row
    unsigned rf = (r < 8.0f) ? (unsigned)(r * 16777216.f) : (2048u << 16);
    if (rf > (2048u << 16)) rf = 2048u << 16;
    pk[e] = make_int2((int)((unsigned)s | ((unsigned)d << 16)), (int)rf);
    atomicAdd(&count[d], 1);
}

// ------------- 2-level exclusive scan over 50000 counts -------------
__global__ void repr_scanA(const int* __restrict__ cnt, int* __restrict__ excl,
                           int* __restrict__ bsum) {
    __shared__ int tmp[256];
    int t = threadIdx.x, b = blockIdx.x;
    int i = b * 256 + t;
    int v = (i < N_NODES) ? cnt[i] : 0;
    tmp[t] = v; __syncthreads();
    for (int off = 1; off < 256; off <<= 1) {
        int add = (t >= off) ? tmp[t - off] : 0;
        __syncthreads();
        tmp[t] += add;
        __syncthreads();
    }
    if (i < N_NODES) excl[i] = tmp[t] - v;
    if (t == 255) bsum[b] = tmp[255];
}
__global__ void repr_scanB(const int* __restrict__ bsum, int* __restrict__ bpref) {
    __shared__ int tmp[256];
    int t = threadIdx.x;
    int v = (t < NCHUNK) ? bsum[t] : 0;
    tmp[t] = v; __syncthreads();
    for (int off = 1; off < 256; off <<= 1) {
        int add = (t >= off) ? tmp[t - off] : 0;
        __syncthreads();
        tmp[t] += add;
        __syncthreads();
    }
    if (t < NCHUNK) bpref[t] = tmp[t] - v;
}
__global__ void repr_scanC(const int* __restrict__ excl, const int* __restrict__ bpref,
                           int* __restrict__ cur) {
    int i = blockIdx.x * 256 + threadIdx.x;
    if (i < N_NODES) cur[i] = excl[i] + bpref[blockIdx.x];
}

// ------------- scatter: dst-sorted packed edge list, one 8B store per edge -------------
__global__ void repr_scatter(const int2* __restrict__ pk,
                             int* __restrict__ cur,
                             int2* __restrict__ surv) {
    int e = blockIdx.x * blockDim.x + threadIdx.x;
    if (e >= N_EDGES) return;
    int2 v = pk[e];
    int d = (int)((unsigned)v.x >> 16);
    int pos = atomicAdd(&cur[d], 1);
    surv[pos] = v;
}

// ================= tiled fp32 node GEMMs (64 nodes / block, 256 threads) =================

// agg holds UNNORMALIZED weighted sums; divide by denom[d] here (deferred softmax).
__device__ __forceinline__ void load_ssp_agg(int base, int tid,
        const float* __restrict__ agg, const float* __restrict__ denom,
        float* __restrict__ bufA) {
    int row = tid >> 2;
    int c0 = (tid & 3) << 5;
    int n = base + row;
    float2 dn = *(const float2*)&denom[2 * (size_t)n];
    float i0v = dn.x > 0.f ? 1.f / dn.x : 0.f;
    float i1v = dn.y > 0.f ? 1.f / dn.y : 0.f;
    float inv = (c0 < 64) ? i0v : i1v;
    const float* ap = agg + (size_t)n * HD + c0;
    float* tp = bufA + row * TLD + c0;
    #pragma unroll
    for (int j = 0; j < 8; j++) {
        float4 v = *(const float4*)(ap + j * 4);
        tp[j*4+0] = sspf(v.x * inv); tp[j*4+1] = sspf(v.y * inv);
        tp[j*4+2] = sspf(v.z * inv); tp[j*4+3] = sspf(v.w * inv);
    }
}

__device__ __forceinline__ void gemm_mlp(int base, int tid,
        const float* __restrict__ w1, const float* __restrict__ b1,
        const float* __restrict__ w2, const float* __restrict__ b2,
        float* __restrict__ x, float* __restrict__ bufA, float* __restrict__ v1s)
{
    const int rg = tid >> 4, cg = tid & 15;
    const int r0 = rg * 4, c0 = cg * 4;
    float acc[4][4];
    #pragma unroll
    for (int r = 0; r < 4; r++)
        #pragma unroll
        for (int c = 0; c < 4; c++) acc[r][c] = 0.f;
    for (int k0 = 0; k0 < 128; k0 += 4) {
        float av[4][4];
        #pragma unroll
        for (int r = 0; r < 4; r++)
            *(float4*)av[r] = *(const float4*)&bufA[(r0 + r) * TLD + k0];
        #pragma unroll
        for (int kk = 0; kk < 4; kk++) {
            float4 wv = *(const float4*)(w1 + (k0 + kk) * 64 + c0);
            float wf[4] = {wv.x, wv.y, wv.z, wv.w};
            #pragma unroll
            for (int r = 0; r < 4; r++)
                #pragma unroll
                for (int c = 0; c < 4; c++)
                    acc[r][c] = fmaf(av[r][kk], wf[c], acc[r][c]);
        }
    }
    {
        float4 bv = *(const float4*)(b1 + c0);
        float ba[4] = {bv.x, bv.y, bv.z, bv.w};
        #pragma unroll
        for (int r = 0; r < 4; r++)
            #pragma unroll
            for (int c = 0; c < 4; c++)
                v1s[(r0 + r) * XLD + c0 + c] = sspf(acc[r][c] + ba[c]);
    }
    __syncthreads();
    float acc2[4][4];
    #pragma unroll
    for (int r = 0; r < 4; r++)
        #pragma unroll
        for (int c = 0; c < 4; c++) acc2[r][c] = 0.f;
    for (int k0 = 0; k0 < 64; k0 += 4) {
        float av[4][4];
        #pragma unroll
        for (int r = 0; r < 4; r++)
            *(float4*)av[r] = *(const float4*)&v1s[(r0 + r) * XLD + k0];
        #pragma unroll
        for (int kk = 0; kk < 4; kk++) {
            float4 wv = *(const float4*)(w2 + (k0 + kk) * 64 + c0);
            float wf[4] = {wv.x, wv.y, wv.z, wv.w};
            #pragma unroll
            for (int r = 0; r < 4; r++)
                #pragma unroll
                for (int c = 0; c < 4; c++)
                    acc2[r][c] = fmaf(av[r][kk], wf[c], acc2[r][c]);
        }
    }
    {
        float4 bv = *(const float4*)(b2 + c0);
        #pragma unroll
        for (int r = 0; r < 4; r++) {
            int n = base + r0 + r;
            float4 xv = *(const float4*)(x + (size_t)n * 64 + c0);
            float4 o;
            o.x = acc2[r][0] + bv.x + xv.x;
            o.y = acc2[r][1] + bv.y + xv.y;
            o.z = acc2[r][2] + bv.z + xv.z;
            o.w = acc2[r][3] + bv.w + xv.w;
            *(float4*)&bufA[(r0 + r) * XLD + c0] = o;
            if (n < N_NODES) *(float4*)(x + (size_t)n * 64 + c0) = o;
        }
    }
    __syncthreads();
}

// h stored packed bf16: hq[n*64 + c/2] = bf16(h[c]) | bf16(h[c+1])<<16
__device__ __forceinline__ void gemm_h(int base, int tid,
        const float* __restrict__ bufA,
        const float* __restrict__ fc_w, const float* __restrict__ attn_l,
        const float* __restrict__ attn_r,
        unsigned int* __restrict__ hq, float* __restrict__ el, float* __restrict__ er)
{
    const int rg = tid >> 4, cg = tid & 15;
    const int r0 = rg * 4, c0 = cg * 8;
    float acc[4][8];
    #pragma unroll
    for (int r = 0; r < 4; r++)
        #pragma unroll
        for (int c = 0; c < 8; c++) acc[r][c] = 0.f;
    for (int k0 = 0; k0 < 64; k0 += 4) {
        float av[4][4];
        #pragma unroll
        for (int r = 0; r < 4; r++)
            *(float4*)av[r] = *(const float4*)&bufA[(r0 + r) * XLD + k0];
        #pragma unroll
        for (int kk = 0; kk < 4; kk++) {
            float4 w0 = *(const float4*)(fc_w + (k0 + kk) * 128 + c0);
            float4 w1v = *(const float4*)(fc_w + (k0 + kk) * 128 + c0 + 4);
            float wf[8] = {w0.x, w0.y, w0.z, w0.w, w1v.x, w1v.y, w1v.z, w1v.w};
            #pragma unroll
            for (int r = 0; r < 4; r++)
                #pragma unroll
                for (int c = 0; c < 8; c++)
                    acc[r][c] = fmaf(av[r][kk], wf[c], acc[r][c]);
        }
    }
    float al[8], ar[8];
    #pragma unroll
    for (int c = 0; c < 8; c++) { al[c] = attn_l[c0 + c]; ar[c] = attn_r[c0 + c]; }
    int head = cg >> 3;
    #pragma unroll
    for (int r = 0; r < 4; r++) {
        int n = base + r0 + r;
        float pel = 0.f, per = 0.f;
        #pragma unroll
        for (int c = 0; c < 8; c++) {
            pel = fmaf(acc[r][c], al[c], pel);
            per = fmaf(acc[r][c], ar[c], per);
        }
        if (n < N_NODES) {
            uint4 pv;
            pv.x = (unsigned int)f2bf(acc[r][0]) | ((unsigned int)f2bf(acc[r][1]) << 16);
            pv.y = (unsigned int)f2bf(acc[r][2]) | ((unsigned int)f2bf(acc[r][3]) << 16);
            pv.z = (unsigned int)f2bf(acc[r][4]) | ((unsigned int)f2bf(acc[r][5]) << 16);
            pv.w = (unsigned int)f2bf(acc[r][6]) | ((unsigned int)f2bf(acc[r][7]) << 16);
            *(uint4*)(hq + (size_t)n * 64 + cg * 4) = pv;
        }
        #pragma unroll
        for (int off = 1; off < 8; off <<= 1) {
            pel += __shfl_xor(pel, off, 64);
            per += __shfl_xor(per, off, 64);
        }
        if ((cg & 7) == 0 && n < N_NODES) {
            el[n * 2 + head] = pel;
            er[n * 2 + head] = per;
        }
    }
}

__global__ __launch_bounds__(256) void repr_embed_h(
        const float* __restrict__ emb, const int* __restrict__ Z,
        const float* __restrict__ fc_w, const float* __restrict__ attn_l,
        const float* __restrict__ attn_r,
        float* __restrict__ x, unsigned int* __restrict__ hq,
        float* __restrict__ el, float* __restrict__ er) {
    __shared__ float bufA[TN * XLD];
    int base = blockIdx.x * TN, tid = threadIdx.x;
    int row = tid >> 2;
    int c0 = (tid & 3) << 4;
    int n = base + row;
    int z = (n < N_NODES) ? Z[n] : 0;
    const float* ep = emb + (size_t)z * D_DIM + c0;
    float* bp = bufA + row * XLD + c0;
    #pragma unroll
    for (int j = 0; j < 4; j++) {
        float4 v = *(const float4*)(ep + j * 4);
        *(float4*)(bp + j * 4) = v;
        if (n < N_NODES) *(float4*)(x + (size_t)n * D_DIM + c0 + j * 4) = v;
    }
    __syncthreads();
    gemm_h(base, tid, bufA, fc_w, attn_l, attn_r, hq, el, er);
}

__global__ __launch_bounds__(256) void repr_mlp_h(
        const float* __restrict__ agg, const float* __restrict__ denom,
        const float* __restrict__ w1, const float* __restrict__ b1,
        const float* __restrict__ w2, const float* __restrict__ b2,
        const float* __restrict__ fc_w, const float* __restrict__ attn_l,
        const float* __restrict__ attn_r,
        float* __restrict__ x, unsigned int* __restrict__ hq,
        float* __restrict__ el, float* __restrict__ er) {
    __shared__ float bufA[TN * TLD];
    __shared__ float v1s[TN * XLD];
    int base = blockIdx.x * TN, tid = threadIdx.x;
    load_ssp_agg(base, tid, agg, denom, bufA);
    __syncthreads();
    gemm_mlp(base, tid, w1, b1, w2, b2, x, bufA, v1s);
    gemm_h(base, tid, bufA, fc_w, attn_l, attn_r, hq, el, er);
}

__global__ __launch_bounds__(256) void repr_mlp_out(
        const float* __restrict__ agg, const float* __restrict__ denom,
        const float* __restrict__ w1, const float* __restrict__ b1,
        const float* __restrict__ w2, const float* __restrict__ b2,
        const float* __restrict__ ow1, const float* __restrict__ ob1,
        const float* __restrict__ ow2, const float* __restrict__ ob2,
        float* __restrict__ x, float* __restrict__ hh) {
    __shared__ float bufA[TN * TLD];
    __shared__ float v1s[TN * XLD];
    int base = blockIdx.x * TN, tid = threadIdx.x;
    load_ssp_agg(base, tid, agg, denom, bufA);
    __syncthreads();
    gemm_mlp(base, tid, w1, b1, w2, b2, x, bufA, v1s);
    const int rg = tid >> 4, cg = tid & 15;
    const int r0 = rg * 4, c0 = cg * 8;
    float acc[4][8];
    #pragma unroll
    for (int r = 0; r < 4; r++)
        #pragma unroll
        for (int c = 0; c < 8; c++) acc[r][c] = 0.f;
    for (int k0 = 0; k0 < 64; k0 += 4) {
        float av[4][4];
        #pragma unroll
        for (int r = 0; r < 4; r++)
            *(float4*)av[r] = *(const float4*)&bufA[(r0 + r) * XLD + k0];
        #pragma unroll
        for (int kk = 0; kk < 4; kk++) {
            float4 w0 = *(const float4*)(ow1 + (k0 + kk) * 128 + c0);
            float4 w1v = *(const float4*)(ow1 + (k0 + kk) * 128 + c0 + 4);
            float wf[8] = {w0.x, w0.y, w0.z, w0.w, w1v.x, w1v.y, w1v.z, w1v.w};
            #pragma unroll
            for (int r = 0; r < 4; r++)
                #pragma unroll
                for (int c = 0; c < 8; c++)
                    acc[r][c] = fmaf(av[r][kk], wf[c], acc[r][c]);
        }
    }
    float o1[8], w2c[8];
    #pragma unroll
    for (int c = 0; c < 8; c++) { o1[c] = ob1[c0 + c]; w2c[c] = ow2[c0 + c]; }
    #pragma unroll
    for (int r = 0; r < 4; r++) {
        int n = base + r0 + r;
        float s = 0.f;
        #pragma unroll
        for (int c = 0; c < 8; c++)
            s = fmaf(sspf(acc[r][c] + o1[c]), w2c[c], s);
        #pragma unroll
        for (int off = 1; off < 16; off <<= 1)
            s += __shfl_xor(s, off, 64);
        if (cg == 0 && n < N_NODES) hh[n] = s + ob2[0];
    }
}

// ------------- LUT message + UNNORMALIZED segmented reduce + denom fusion ----------
// 256 threads = 64 col-pairs x 4 row-subranges of 32 edges; TILE=128 edges.
// All 800k edges (r>=8 hits the zeros LUT row -> 0 into agg, exp feeds denom).
// Denominator: segment-head lanes (LDS-detected, works across wave boundary)
// sum staged exps per dst-run, one global atomicAdd pair per (segment, tile).
// agg flushes: interior segments plain-store; subrange/tile boundaries atomic
// (agg pre-zeroed by repr_zero).
#define TILE 128
__global__ __launch_bounds__(256) void repr_msg_lut(
    const int2* __restrict__ surv,
    const float* __restrict__ el, const float* __restrict__ er,
    const unsigned int* __restrict__ hq,
    const unsigned int* __restrict__ lut,
    float* __restrict__ agg, float* __restrict__ denom)
{
    __shared__ int4 rowinfo[TILE];     // {lut row i0, src, dst, frac bits}
    __shared__ float scl[TILE][2];     // exp(leaky(el+er)) per head
    int base = blockIdx.x * TILE;
    int tid = threadIdx.x;
    int d_own = -1; float e0 = 0.f, e1 = 0.f;
    if (tid < TILE) {
        int2 ev = surv[base + tid];
        int sn = (int)((unsigned)ev.x & 0xFFFFu);
        d_own  = (int)((unsigned)ev.x >> 16);
        unsigned rf = (unsigned)ev.y;
        int i0 = (int)(rf >> 16);
        float fr = (float)(rf & 0xFFFFu) * (1.f / 65536.f);
        float2 a = *(const float2*)&el[2 * sn];
        float2 b = *(const float2*)&er[2 * d_own];
        float v0 = a.x + b.x; v0 = v0 >= 0.f ? v0 : 0.2f * v0;
        float v1 = a.y + b.y; v1 = v1 >= 0.f ? v1 : 0.2f * v1;
        e0 = __expf(v0); e1 = __expf(v1);
        rowinfo[tid] = make_int4(i0, sn, d_own, __float_as_int(fr));
        scl[tid][0] = e0; scl[tid][1] = e1;
    }
    __syncthreads();
    // segment-head lanes accumulate this tile's denom contribution
    if (tid < TILE) {
        bool headl = (tid == 0) || (rowinfo[tid - 1].z != d_own);
        if (headl) {
            float s0 = e0, s1 = e1;
            for (int r = tid + 1; r < TILE; r++) {
                if (rowinfo[r].z != d_own) break;
                s0 += scl[r][0]; s1 += scl[r][1];
            }
            atomicAdd(&denom[2 * d_own], s0);
            atomicAdd(&denom[2 * d_own + 1], s1);
        }
    }
    const int cp = tid & 63;           // col pair: cols 2cp, 2cp+1
    const int sp = tid >> 6;           // row-subrange: rows [sp*32, sp*32+32)
    const int head = cp >> 5;          // cols 0-63 head0, 64-127 head1
    const int lo = sp * 32;
    const uint2* __restrict__ l2p = (const uint2*)lut;
    float sum0 = 0.f, sum1 = 0.f;
    int cur_d = -1;
    int seg_first = 1;                 // current segment started at subrange begin
    #pragma unroll 4
    for (int j = 0; j < 32; j++) {
        int r = lo + j;
        int4 ri = rowinfo[r];          // wave-uniform LDS broadcast
        if (ri.z != cur_d) {
            if (cur_d >= 0) {
                float* ap = &agg[(size_t)cur_d * HD + 2 * cp];
                // segment possibly extends into previous subrange/block -> atomic
                if (seg_first) { atomicAdd(ap, sum0); atomicAdd(ap + 1, sum1); }
                else *(float2*)ap = make_float2(sum0, sum1);
            }
            cur_d = ri.z; sum0 = 0.f; sum1 = 0.f; seg_first = (j == 0);
        }
        uint2 tv = l2p[(size_t)ri.x * 64 + cp];
        float fr = __int_as_float(ri.w);
        float wa0 = __uint_as_float(tv.x << 16);
        float wa1 = __uint_as_float(tv.x & 0xFFFF0000u);
        float wb0 = __uint_as_float(tv.y << 16);
        float wb1 = __uint_as_float(tv.y & 0xFFFF0000u);
        unsigned int hv = hq[(size_t)ri.y * 64 + cp];
        float ha = __uint_as_float(hv << 16);
        float hb = __uint_as_float(hv & 0xFFFF0000u);
        float s = scl[r][head];
        float wa = fmaf(fr, wa1 - wa0, wa0);
        float wb = fmaf(fr, wb1 - wb0, wb0);
        sum0 = fmaf(wa * ha, s, sum0);
        sum1 = fmaf(wb * hb, s, sum1);
    }
    // trailing segment may continue into next subrange/block -> atomic
    if (cur_d >= 0) {
        float* ap = &agg[(size_t)cur_d * HD + 2 * cp];
        atomicAdd(ap, sum0); atomicAdd(ap + 1, sum1);
    }
}

// ------------- graph segment-sum with LDS privatization -> d_out directly -------------
__global__ void repr_gsum(const float* __restrict__ hh, const int* __restrict__ gids,
                          float* __restrict__ dout) {
    __shared__ float bins[B_GRAPHS];
    int t = threadIdx.x;
    if (t < B_GRAPHS) bins[t] = 0.f;
    __syncthreads();
    int i = blockIdx.x * 256 + t;
    if (i < N_NODES) atomicAdd(&bins[gids[i]], hh[i]);
    __syncthreads();
    if (t < B_GRAPHS && bins[t] != 0.f) atomicAdd(&dout[t], bins[t]);
}

extern "C" void kernel_launch(void* const* d_in, const int* in_sizes, int n_in,
                              void* d_out, int out_size, void* d_ws, size_t ws_size,
                              hipStream_t stream) {
    (void)in_sizes; (void)n_in; (void)out_size; (void)ws_size;
    const float* R      = (const float*)d_in[0];
    const int*   Z      = (const int*)d_in[1];
    const int*   src    = (const int*)d_in[2];
    const int*   dst    = (const int*)d_in[3];
    const int*   gids   = (const int*)d_in[4];
    const float* emb    = (const float*)d_in[5];
    const float* offs   = (const float*)d_in[6];
    const float* widths = (const float*)d_in[7];
    const float* fc_w   = (const float*)d_in[8];
    const float* attn_l = (const float*)d_in[9];
    const float* attn_r = (const float*)d_in[10];
    const float* fw1    = (const float*)d_in[11];
    const float* fb1    = (const float*)d_in[12];
    const float* fw2    = (const float*)d_in[13];
    const float* fb2    = (const float*)d_in[14];
    const float* mw1    = (const float*)d_in[15];
    const float* mb1    = (const float*)d_in[16];
    const float* mw2    = (const float*)d_in[17];
    const float* mb2    = (const float*)d_in[18];
    const float* ow1    = (const float*)d_in[19];
    const float* ob1    = (const float*)d_in[20];
    const float* ow2    = (const float*)d_in[21];
    const float* ob2    = (const float*)d_in[22];

    char* p = (char*)d_ws;
    float* x      = (float*)p; p += (size_t)N_NODES * 64 * 4;
    unsigned int* hq = (unsigned int*)p; p += (size_t)N_NODES * 64 * 4;  // packed bf16 pairs
    float* el     = (float*)p; p += (size_t)N_NODES * 2 * 4;
    float* er     = (float*)p; p += (size_t)N_NODES * 2 * 4;
    float* denom  = (float*)p; p += (size_t)N_NODES * 2 * 4;
    float* agg    = (float*)p; p += (size_t)N_NODES * 128 * 4;
    int2*  surv   = (int2*)p;  p += (size_t)N_EDGES * 8;
    int2*  pk     = (int2*)p;  p += (size_t)N_EDGES * 8;
    float* hh     = (float*)p; p += (size_t)N_NODES * 4;
    int*   bsum   = (int*)p;   p += 1024;
    int*   bpref  = (int*)p;   p += 1024;
    // filter-net LUT aliases pk: 3*2049*128*4 = 3,147,264 B <= 6,400,000 B.
    // pk is dead after repr_scatter; lut is built strictly after it.
    unsigned int* lut = (unsigned int*)pk;
    // scan temporaries aliased into x (x written by repr_embed_h, strictly after
    // repr_scatter in stream order):
    int* count = (int*)x;
    int* excl  = (int*)((char*)x + 256 * 1024);
    int* cur   = (int*)((char*)x + 512 * 1024);

    // one-time prep: zero edge counter + d_out
    repr_prep<<<(N_NODES + B_GRAPHS + 255) / 256, 256, 0, stream>>>(
        count, (float*)d_out);
    repr_hist<<<N_EDGES / 256, 256, 0, stream>>>(R, src, dst, count, pk);
    repr_scanA<<<NCHUNK, 256, 0, stream>>>(count, excl, bsum);
    repr_scanB<<<1, 256, 0, stream>>>(bsum, bpref);
    repr_scanC<<<NCHUNK, 256, 0, stream>>>(excl, bpref, cur);
    repr_scatter<<<N_EDGES / 256, 256, 0, stream>>>(pk, cur, surv);

    // build the w(r)*C(r) tables (pk is dead from here on)
    repr_lut_build<<<L_LAYERS * (LUT_T / LROWS), 256, 0, stream>>>(
        offs, widths, fw1, fb1, fw2, fb2, lut);

    repr_embed_h<<<NBLK, 256, 0, stream>>>(
        emb, Z, fc_w, attn_l, attn_r, x, hq, el, er);

    for (int l = 0; l < L_LAYERS; l++) {
        repr_zero<<<(ZTOT + 255) / 256, 256, 0, stream>>>(agg, denom);
        repr_msg_lut<<<N_EDGES / TILE, 256, 0, stream>>>(
            surv, el, er, hq, lut + (size_t)l * LUT_ROWS * HD, agg, denom);
        if (l < L_LAYERS - 1) {
            repr_mlp_h<<<NBLK, 256, 0, stream>>>(
                agg, denom, mw1 + (size_t)l * 128 * 64, mb1 + l * 64,
                mw2 + (size_t)l * 64 * 64, mb2 + l * 64,
                fc_w + (size_t)(l + 1) * 64 * 128, attn_l + (l + 1) * 128,
                attn_r + (l + 1) * 128, x, hq, el, er);
        } else {
            repr_mlp_out<<<NBLK, 256, 0, stream>>>(
                agg, denom, mw1 + (size_t)l * 128 * 64, mb1 + l * 64,
                mw2 + (size_t)l * 64 * 64, mb2 + l * 64,
                ow1, ob1, ow2, ob2, x, hh);
        }
    }
    repr_gsum<<<NCHUNK, 256, 0, stream>>>(hh, gids, (float*)d_out);
}

// Round 12
// 624.418 us; speedup vs baseline: 3.3914x; 1.0229x over previous
//
#include <hip/hip_runtime.h>
#include <stdint.h>

#define N_NODES 50000
#define N_EDGES 800000
#define B_GRAPHS 64
#define D_DIM 64
#define HD 128
#define G_GAUSS 50
#define HID_DIM 128
#define L_LAYERS 3
#define LN2 0.69314718055994530942f
#define PI_OVER_8 0.39269908169872414f
#define NCHUNK 196            // ceil(50000/256)

#define TN 64                 // nodes per node-GEMM block
#define TLD 132               // fp32 LDS leading dim for 128-wide tiles
#define XLD 68                // fp32 LDS leading dim for 64-wide tiles
#define NBLK ((N_NODES + TN - 1) / TN)   // 782

// filter-net lookup table: w(r)*C(r) over r in [0,8), linear interpolation.
// Rows 0..LUT_T-1 cover [0,8); row LUT_T is all-zero (r>=8 cutoff folded in).
#define LUT_T 2048
#define LUT_ROWS (LUT_T + 1)
#define LROWS 8               // table rows built per block

__device__ __forceinline__ float sspf(float x) {
    float ax = fabsf(x);
    return fmaxf(x, 0.f) + __logf(1.f + __expf(-ax)) - LN2;
}
__device__ __forceinline__ unsigned short f2bf(float f) {
    union { float f; unsigned int i; } v; v.f = f;
    unsigned int u = v.i;
    return (unsigned short)((u + 0x7FFFu + ((u >> 16) & 1u)) >> 16);
}

// ------------- one-time: zero edge counter + output -------------
__global__ void repr_prep(int* __restrict__ count, float* __restrict__ dout) {
    int i = blockIdx.x * 256 + threadIdx.x;
    if (i < N_NODES) count[i] = 0;
    else if (i < N_NODES + B_GRAPHS) dout[i - N_NODES] = 0.f;
}

// ------------- per-layer: zero agg (50000x128) + denom (100000) -------------
#define ZTOT ((N_NODES * HD + 2 * N_NODES) / 4)   // float4 count = 1,625,000
__global__ void repr_zero(float* __restrict__ agg, float* __restrict__ denom) {
    int i = blockIdx.x * 256 + threadIdx.x;
    float4 z = make_float4(0.f, 0.f, 0.f, 0.f);
    if (i < N_NODES * HD / 4) ((float4*)agg)[i] = z;
    else if (i < ZTOT) ((float4*)denom)[i - N_NODES * HD / 4] = z;
}

// ------------- one-time: build wc(r) = (ssp(gs@W1+b1)@W2 + b2) * C(r) table -------------
// interleaved bf16: lut[l][i][c] = bf16(wc[i][c]) | bf16(wc[i+1][c])<<16
__global__ __launch_bounds__(256) void repr_lut_build(
    const float* __restrict__ offs, const float* __restrict__ widths,
    const float* __restrict__ fw1, const float* __restrict__ fb1,
    const float* __restrict__ fw2, const float* __restrict__ fb2,
    unsigned int* __restrict__ lut)
{
    __shared__ float gs_s[LROWS + 1][G_GAUSS];
    __shared__ float hid_s[LROWS + 1][HID_DIM];
    __shared__ float wc_s[LROWS + 1][HD];
    const int nb = LUT_T / LROWS;            // 256 blocks per layer
    int l = blockIdx.x / nb;
    int i0r = (blockIdx.x % nb) * LROWS;
    int tid = threadIdx.x;
    const float step = 8.0f / LUT_T;

    for (int j = tid; j < (LROWS + 1) * G_GAUSS; j += 256) {
        int r = j / G_GAUSS, k = j - r * G_GAUSS;
        float rr = (i0r + r) * step;
        float wdt = widths[k];
        float dr = rr - offs[k];
        gs_s[r][k] = expf(-0.5f / (wdt * wdt) * dr * dr);
    }
    __syncthreads();

    int c = tid & 127, sub = tid >> 7;
    int rlo = sub * 4;                       // rows 0..4 / 4..8 (row 4 dup, benign)
    {
        const float* W1 = fw1 + (size_t)l * G_GAUSS * HID_DIM + c;
        float acc[5];
        float bb = fb1[l * HID_DIM + c];
        #pragma unroll
        for (int r = 0; r < 5; r++) acc[r] = bb;
        for (int k = 0; k < G_GAUSS; k++) {
            float wv = W1[k * HID_DIM];
            #pragma unroll
            for (int r = 0; r < 5; r++)
                acc[r] = fmaf(gs_s[rlo + r][k], wv, acc[r]);
        }
        #pragma unroll
        for (int r = 0; r < 5; r++) hid_s[rlo + r][c] = sspf(acc[r]);
    }
    __syncthreads();
    {
        const float* W2 = fw2 + (size_t)l * HID_DIM * HD + c;
        float acc[5];
        float bb = fb2[l * HD + c];
        #pragma unroll
        for (int r = 0; r < 5; r++) acc[r] = bb;
        for (int k = 0; k < HID_DIM; k++) {
            float wv = W2[k * HD];
            #pragma unroll
            for (int r = 0; r < 5; r++)
                acc[r] = fmaf(hid_s[rlo + r][k], wv, acc[r]);
        }
        #pragma unroll
        for (int r = 0; r < 5; r++) {
            float rr = (i0r + rlo + r) * step;
            float C = (rr < 8.0f) ? 0.5f * (cosf(rr * PI_OVER_8) + 1.f) : 0.f;
            wc_s[rlo + r][c] = acc[r] * C;
        }
    }
    __syncthreads();
    for (int j = tid; j < LROWS * HD; j += 256) {
        int r = j >> 7, cc = j & 127;
        unsigned int lo = f2bf(wc_s[r][cc]);
        unsigned int hi = f2bf(wc_s[r + 1][cc]);
        lut[((size_t)l * LUT_ROWS + i0r + r) * HD + cc] = lo | (hi << 16);
    }
    // last block of each layer writes the zeros row (r >= 8 cutoff)
    if (i0r == LUT_T - LROWS && tid < HD)
        lut[((size_t)l * LUT_ROWS + LUT_T) * HD + tid] = 0u;
}

// ------------- histogram + pack {src|dst<<16, r fixed-point} per edge -------------
__global__ void repr_hist(const float* __restrict__ R,
                          const int* __restrict__ src, const int* __restrict__ dst,
                          int* __restrict__ count,
                          int2* __restrict__ pk) {
    int e = blockIdx.x * blockDim.x + threadIdx.x;
    if (e >= N_EDGES) return;
    int s = src[e], d = dst[e];
    float dx = R[3*s+0] - R[3*d+0];
    float dy = R[3*s+1] - R[3*d+1];
    float dz = R[3*s+2] - R[3*d+2];
    float r = sqrtf(dx*dx + dy*dy + dz*dz);
    // r*2^24; i0 = rf>>16 in [0,2047] for r<8, else 2048 -> zeros row
    unsigned rf = (r < 8.0f) ? (unsigned)(r * 16777216.f) : (2048u << 16);
    if (rf > (2048u << 16)) rf = 2048u << 16;
    pk[e] = make_int2((int)((unsigned)s | ((unsigned)d << 16)), (int)rf);
    atomicAdd(&count[d], 1);
}

// ------------- 2-level exclusive scan over 50000 counts -------------
__global__ void repr_scanA(const int* __restrict__ cnt, int* __restrict__ excl,
                           int* __restrict__ bsum) {
    __shared__ int tmp[256];
    int t = threadIdx.x, b = blockIdx.x;
    int i = b * 256 + t;
    int v = (i < N_NODES) ? cnt[i] : 0;
    tmp[t] = v; __syncthreads();
    for (int off = 1; off < 256; off <<= 1) {
        int add = (t >= off) ? tmp[t - off] : 0;
        __syncthreads();
        tmp[t] += add;
        __syncthreads();
    }
    if (i < N_NODES) excl[i] = tmp[t] - v;
    if (t == 255) bsum[b] = tmp[255];
}
__global__ void repr_scanB(const int* __restrict__ bsum, int* __restrict__ bpref) {
    __shared__ int tmp[256];
    int t = threadIdx.x;
    int v = (t < NCHUNK) ? bsum[t] : 0;
    tmp[t] = v; __syncthreads();
    for (int off = 1; off < 256; off <<= 1) {
        int add = (t >= off) ? tmp[t - off] : 0;
        __syncthreads();
        tmp[t] += add;
        __syncthreads();
    }
    if (t < NCHUNK) bpref[t] = tmp[t] - v;
}
__global__ void repr_scanC(const int* __restrict__ excl, const int* __restrict__ bpref,
                           int* __restrict__ cur) {
    int i = blockIdx.x * 256 + threadIdx.x;
    if (i < N_NODES) cur[i] = excl[i] + bpref[blockIdx.x];
}

// ------------- scatter: dst-sorted packed edge list, one 8B store per edge -------------
__global__ void repr_scatter(const int2* __restrict__ pk,
                             int* __restrict__ cur,
                             int2* __restrict__ surv) {
    int e = blockIdx.x * blockDim.x + threadIdx.x;
    if (e >= N_EDGES) return;
    int2 v = pk[e];
    int d = (int)((unsigned)v.x >> 16);
    int pos = atomicAdd(&cur[d], 1);
    surv[pos] = v;
}

// ================= tiled fp32 node GEMMs (64 nodes / block, 256 threads) =================

// agg holds UNNORMALIZED weighted sums; divide by denom[d] here (deferred softmax).
__device__ __forceinline__ void load_ssp_agg(int base, int tid,
        const float* __restrict__ agg, const float* __restrict__ denom,
        float* __restrict__ bufA) {
    int row = tid >> 2;
    int c0 = (tid & 3) << 5;
    int n = base + row;
    float2 dn = *(const float2*)&denom[2 * (size_t)n];
    float i0v = dn.x > 0.f ? 1.f / dn.x : 0.f;
    float i1v = dn.y > 0.f ? 1.f / dn.y : 0.f;
    float inv = (c0 < 64) ? i0v : i1v;
    const float* ap = agg + (size_t)n * HD + c0;
    float* tp = bufA + row * TLD + c0;
    #pragma unroll
    for (int j = 0; j < 8; j++) {
        float4 v = *(const float4*)(ap + j * 4);
        tp[j*4+0] = sspf(v.x * inv); tp[j*4+1] = sspf(v.y * inv);
        tp[j*4+2] = sspf(v.z * inv); tp[j*4+3] = sspf(v.w * inv);
    }
}

__device__ __forceinline__ void gemm_mlp(int base, int tid,
        const float* __restrict__ w1, const float* __restrict__ b1,
        const float* __restrict__ w2, const float* __restrict__ b2,
        float* __restrict__ x, float* __restrict__ bufA, float* __restrict__ v1s)
{
    const int rg = tid >> 4, cg = tid & 15;
    const int r0 = rg * 4, c0 = cg * 4;
    float acc[4][4];
    #pragma unroll
    for (int r = 0; r < 4; r++)
        #pragma unroll
        for (int c = 0; c < 4; c++) acc[r][c] = 0.f;
    for (int k0 = 0; k0 < 128; k0 += 4) {
        float av[4][4];
        #pragma unroll
        for (int r = 0; r < 4; r++)
            *(float4*)av[r] = *(const float4*)&bufA[(r0 + r) * TLD + k0];
        #pragma unroll
        for (int kk = 0; kk < 4; kk++) {
            float4 wv = *(const float4*)(w1 + (k0 + kk) * 64 + c0);
            float wf[4] = {wv.x, wv.y, wv.z, wv.w};
            #pragma unroll
            for (int r = 0; r < 4; r++)
                #pragma unroll
                for (int c = 0; c < 4; c++)
                    acc[r][c] = fmaf(av[r][kk], wf[c], acc[r][c]);
        }
    }
    {
        float4 bv = *(const float4*)(b1 + c0);
        float ba[4] = {bv.x, bv.y, bv.z, bv.w};
        #pragma unroll
        for (int r = 0; r < 4; r++)
            #pragma unroll
            for (int c = 0; c < 4; c++)
                v1s[(r0 + r) * XLD + c0 + c] = sspf(acc[r][c] + ba[c]);
    }
    __syncthreads();
    float acc2[4][4];
    #pragma unroll
    for (int r = 0; r < 4; r++)
        #pragma unroll
        for (int c = 0; c < 4; c++) acc2[r][c] = 0.f;
    for (int k0 = 0; k0 < 64; k0 += 4) {
        float av[4][4];
        #pragma unroll
        for (int r = 0; r < 4; r++)
            *(float4*)av[r] = *(const float4*)&v1s[(r0 + r) * XLD + k0];
        #pragma unroll
        for (int kk = 0; kk < 4; kk++) {
            float4 wv = *(const float4*)(w2 + (k0 + kk) * 64 + c0);
            float wf[4] = {wv.x, wv.y, wv.z, wv.w};
            #pragma unroll
            for (int r = 0; r < 4; r++)
                #pragma unroll
                for (int c = 0; c < 4; c++)
                    acc2[r][c] = fmaf(av[r][kk], wf[c], acc2[r][c]);
        }
    }
    {
        float4 bv = *(const float4*)(b2 + c0);
        #pragma unroll
        for (int r = 0; r < 4; r++) {
            int n = base + r0 + r;
            float4 xv = *(const float4*)(x + (size_t)n * 64 + c0);
            float4 o;
            o.x = acc2[r][0] + bv.x + xv.x;
            o.y = acc2[r][1] + bv.y + xv.y;
            o.z = acc2[r][2] + bv.z + xv.z;
            o.w = acc2[r][3] + bv.w + xv.w;
            *(float4*)&bufA[(r0 + r) * XLD + c0] = o;
            if (n < N_NODES) *(float4*)(x + (size_t)n * 64 + c0) = o;
        }
    }
    __syncthreads();
}

// h stored packed bf16: hq[n*64 + c/2] = bf16(h[c]) | bf16(h[c+1])<<16
__device__ __forceinline__ void gemm_h(int base, int tid,
        const float* __restrict__ bufA,
        const float* __restrict__ fc_w, const float* __restrict__ attn_l,
        const float* __restrict__ attn_r,
        unsigned int* __restrict__ hq, float* __restrict__ el, float* __restrict__ er)
{
    const int rg = tid >> 4, cg = tid & 15;
    const int r0 = rg * 4, c0 = cg * 8;
    float acc[4][8];
    #pragma unroll
    for (int r = 0; r < 4; r++)
        #pragma unroll
        for (int c = 0; c < 8; c++) acc[r][c] = 0.f;
    for (int k0 = 0; k0 < 64; k0 += 4) {
        float av[4][4];
        #pragma unroll
        for (int r = 0; r < 4; r++)
            *(float4*)av[r] = *(const float4*)&bufA[(r0 + r) * XLD + k0];
        #pragma unroll
        for (int kk = 0; kk < 4; kk++) {
            float4 w0 = *(const float4*)(fc_w + (k0 + kk) * 128 + c0);
            float4 w1v = *(const float4*)(fc_w + (k0 + kk) * 128 + c0 + 4);
            float wf[8] = {w0.x, w0.y, w0.z, w0.w, w1v.x, w1v.y, w1v.z, w1v.w};
            #pragma unroll
            for (int r = 0; r < 4; r++)
                #pragma unroll
                for (int c = 0; c < 8; c++)
                    acc[r][c] = fmaf(av[r][kk], wf[c], acc[r][c]);
        }
    }
    float al[8], ar[8];
    #pragma unroll
    for (int c = 0; c < 8; c++) { al[c] = attn_l[c0 + c]; ar[c] = attn_r[c0 + c]; }
    int head = cg >> 3;
    #pragma unroll
    for (int r = 0; r < 4; r++) {
        int n = base + r0 + r;
        float pel = 0.f, per = 0.f;
        #pragma unroll
        for (int c = 0; c < 8; c++) {
            pel = fmaf(acc[r][c], al[c], pel);
            per = fmaf(acc[r][c], ar[c], per);
        }
        if (n < N_NODES) {
            uint4 pv;
            pv.x = (unsigned int)f2bf(acc[r][0]) | ((unsigned int)f2bf(acc[r][1]) << 16);
            pv.y = (unsigned int)f2bf(acc[r][2]) | ((unsigned int)f2bf(acc[r][3]) << 16);
            pv.z = (unsigned int)f2bf(acc[r][4]) | ((unsigned int)f2bf(acc[r][5]) << 16);
            pv.w = (unsigned int)f2bf(acc[r][6]) | ((unsigned int)f2bf(acc[r][7]) << 16);
            *(uint4*)(hq + (size_t)n * 64 + cg * 4) = pv;
        }
        #pragma unroll
        for (int off = 1; off < 8; off <<= 1) {
            pel += __shfl_xor(pel, off, 64);
            per += __shfl_xor(per, off, 64);
        }
        if ((cg & 7) == 0 && n < N_NODES) {
            el[n * 2 + head] = pel;
            er[n * 2 + head] = per;
        }
    }
}

__global__ __launch_bounds__(256) void repr_embed_h(
        const float* __restrict__ emb, const int* __restrict__ Z,
        const float* __restrict__ fc_w, const float* __restrict__ attn_l,
        const float* __restrict__ attn_r,
        float* __restrict__ x, unsigned int* __restrict__ hq,
        float* __restrict__ el, float* __restrict__ er) {
    __shared__ float bufA[TN * XLD];
    int base = blockIdx.x * TN, tid = threadIdx.x;
    int row = tid >> 2;
    int c0 = (tid & 3) << 4;
    int n = base + row;
    int z = (n < N_NODES) ? Z[n] : 0;
    const float* ep = emb + (size_t)z * D_DIM + c0;
    float* bp = bufA + row * XLD + c0;
    #pragma unroll
    for (int j = 0; j < 4; j++) {
        float4 v = *(const float4*)(ep + j * 4);
        *(float4*)(bp + j * 4) = v;
        if (n < N_NODES) *(float4*)(x + (size_t)n * D_DIM + c0 + j * 4) = v;
    }
    __syncthreads();
    gemm_h(base, tid, bufA, fc_w, attn_l, attn_r, hq, el, er);
}

__global__ __launch_bounds__(256) void repr_mlp_h(
        const float* __restrict__ agg, const float* __restrict__ denom,
        const float* __restrict__ w1, const float* __restrict__ b1,
        const float* __restrict__ w2, const float* __restrict__ b2,
        const float* __restrict__ fc_w, const float* __restrict__ attn_l,
        const float* __restrict__ attn_r,
        float* __restrict__ x, unsigned int* __restrict__ hq,
        float* __restrict__ el, float* __restrict__ er) {
    __shared__ float bufA[TN * TLD];
    __shared__ float v1s[TN * XLD];
    int base = blockIdx.x * TN, tid = threadIdx.x;
    load_ssp_agg(base, tid, agg, denom, bufA);
    __syncthreads();
    gemm_mlp(base, tid, w1, b1, w2, b2, x, bufA, v1s);
    gemm_h(base, tid, bufA, fc_w, attn_l, attn_r, hq, el, er);
}

__global__ __launch_bounds__(256) void repr_mlp_out(
        const float* __restrict__ agg, const float* __restrict__ denom,
        const float* __restrict__ w1, const float* __restrict__ b1,
        const float* __restrict__ w2, const float* __restrict__ b2,
        const float* __restrict__ ow1, const float* __restrict__ ob1,
        const float* __restrict__ ow2, const float* __restrict__ ob2,
        float* __restrict__ x, float* __restrict__ hh) {
    __shared__ float bufA[TN * TLD];
    __shared__ float v1s[TN * XLD];
    int base = blockIdx.x * TN, tid = threadIdx.x;
    load_ssp_agg(base, tid, agg, denom, bufA);
    __syncthreads();
    gemm_mlp(base, tid, w1, b1, w2, b2, x, bufA, v1s);
    const int rg = tid >> 4, cg = tid & 15;
    const int r0 = rg * 4, c0 = cg * 8;
    float acc[4][8];
    #pragma unroll
    for (int r = 0; r < 4; r++)
        #pragma unroll
        for (int c = 0; c < 8; c++) acc[r][c] = 0.f;
    for (int k0 = 0; k0 < 64; k0 += 4) {
        float av[4][4];
        #pragma unroll
        for (int r = 0; r < 4; r++)
            *(float4*)av[r] = *(const float4*)&bufA[(r0 + r) * XLD + k0];
        #pragma unroll
        for (int kk = 0; kk < 4; kk++) {
            float4 w0 = *(const float4*)(ow1 + (k0 + kk) * 128 + c0);
            float4 w1v = *(const float4*)(ow1 + (k0 + kk) * 128 + c0 + 4);
            float wf[8] = {w0.x, w0.y, w0.z, w0.w, w1v.x, w1v.y, w1v.z, w1v.w};
            #pragma unroll
            for (int r = 0; r < 4; r++)
                #pragma unroll
                for (int c = 0; c < 8; c++)
                    acc[r][c] = fmaf(av[r][kk], wf[c], acc[r][c]);
        }
    }
    float o1[8], w2c[8];
    #pragma unroll
    for (int c = 0; c < 8; c++) { o1[c] = ob1[c0 + c]; w2c[c] = ow2[c0 + c]; }
    #pragma unroll
    for (int r = 0; r < 4; r++) {
        int n = base + r0 + r;
        float s = 0.f;
        #pragma unroll
        for (int c = 0; c < 8; c++)
            s = fmaf(sspf(acc[r][c] + o1[c]), w2c[c], s);
        #pragma unroll
        for (int off = 1; off < 16; off <<= 1)
            s += __shfl_xor(s, off, 64);
        if (cg == 0 && n < N_NODES) hh[n] = s + ob2[0];
    }
}

// ------------- LUT message + UNNORMALIZED segmented reduce + denom fusion ----------
// TILE=256 edges (800000/256 = 3125 tiles, exact); 256 threads =
// 64 col-pairs x 4 row-subranges of 64 edges. All 800k edges (r>=8 hits the
// zeros LUT row -> 0 into agg, exp feeds denom).
// Denominator: segment-head lanes (LDS-detected, works across wave boundary)
// sum staged exps per dst-run, one global atomicAdd pair per (segment, tile).
// agg flushes: interior segments plain-store; subrange/tile boundaries atomic
// (agg pre-zeroed by repr_zero).
#define TILE 256
__global__ __launch_bounds__(256) void repr_msg_lut(
    const int2* __restrict__ surv,
    const float* __restrict__ el, const float* __restrict__ er,
    const unsigned int* __restrict__ hq,
    const unsigned int* __restrict__ lut,
    float* __restrict__ agg, float* __restrict__ denom)
{
    __shared__ int4 rowinfo[TILE];     // {lut row i0, src, dst, frac bits}
    __shared__ float scl[TILE][2];     // exp(leaky(el+er)) per head
    int base = blockIdx.x * TILE;
    int tid = threadIdx.x;
    int d_own; float e0, e1;
    {
        int2 ev = surv[base + tid];
        int sn = (int)((unsigned)ev.x & 0xFFFFu);
        d_own  = (int)((unsigned)ev.x >> 16);
        unsigned rf = (unsigned)ev.y;
        int i0 = (int)(rf >> 16);
        float fr = (float)(rf & 0xFFFFu) * (1.f / 65536.f);
        float2 a = *(const float2*)&el[2 * sn];
        float2 b = *(const float2*)&er[2 * d_own];
        float v0 = a.x + b.x; v0 = v0 >= 0.f ? v0 : 0.2f * v0;
        float v1 = a.y + b.y; v1 = v1 >= 0.f ? v1 : 0.2f * v1;
        e0 = __expf(v0); e1 = __expf(v1);
        rowinfo[tid] = make_int4(i0, sn, d_own, __float_as_int(fr));
        scl[tid][0] = e0; scl[tid][1] = e1;
    }
    __syncthreads();
    // segment-head lanes accumulate this tile's denom contribution
    {
        bool headl = (tid == 0) || (rowinfo[tid - 1].z != d_own);
        if (headl) {
            float s0 = e0, s1 = e1;
            for (int r = tid + 1; r < TILE; r++) {
                if (rowinfo[r].z != d_own) break;
                s0 += scl[r][0]; s1 += scl[r][1];
            }
            atomicAdd(&denom[2 * d_own], s0);
            atomicAdd(&denom[2 * d_own + 1], s1);
        }
    }
    const int cp = tid & 63;           // col pair: cols 2cp, 2cp+1
    const int sp = tid >> 6;           // row-subrange: rows [sp*64, sp*64+64)
    const int head = cp >> 5;          // cols 0-63 head0, 64-127 head1
    const int lo = sp * 64;
    const uint2* __restrict__ l2p = (const uint2*)lut;
    float sum0 = 0.f, sum1 = 0.f;
    int cur_d = -1;
    int seg_first = 1;                 // current segment started at subrange begin
    #pragma unroll 4
    for (int j = 0; j < 64; j++) {
        int r = lo + j;
        int4 ri = rowinfo[r];          // wave-uniform LDS broadcast
        if (ri.z != cur_d) {
            if (cur_d >= 0) {
                float* ap = &agg[(size_t)cur_d * HD + 2 * cp];
                // segment possibly extends into previous subrange/block -> atomic
                if (seg_first) { atomicAdd(ap, sum0); atomicAdd(ap + 1, sum1); }
                else *(float2*)ap = make_float2(sum0, sum1);
            }
            cur_d = ri.z; sum0 = 0.f; sum1 = 0.f; seg_first = (j == 0);
        }
        uint2 tv = l2p[(size_t)ri.x * 64 + cp];
        float fr = __int_as_float(ri.w);
        float wa0 = __uint_as_float(tv.x << 16);
        float wa1 = __uint_as_float(tv.x & 0xFFFF0000u);
        float wb0 = __uint_as_float(tv.y << 16);
        float wb1 = __uint_as_float(tv.y & 0xFFFF0000u);
        unsigned int hv = hq[(size_t)ri.y * 64 + cp];
        float ha = __uint_as_float(hv << 16);
        float hb = __uint_as_float(hv & 0xFFFF0000u);
        float s = scl[r][head];
        float wa = fmaf(fr, wa1 - wa0, wa0);
        float wb = fmaf(fr, wb1 - wb0, wb0);
        sum0 = fmaf(wa * ha, s, sum0);
        sum1 = fmaf(wb * hb, s, sum1);
    }
    // trailing segment may continue into next subrange/block -> atomic
    if (cur_d >= 0) {
        float* ap = &agg[(size_t)cur_d * HD + 2 * cp];
        atomicAdd(ap, sum0); atomicAdd(ap + 1, sum1);
    }
}

// ------------- graph segment-sum with LDS privatization -> d_out directly -------------
__global__ void repr_gsum(const float* __restrict__ hh, const int* __restrict__ gids,
                          float* __restrict__ dout) {
    __shared__ float bins[B_GRAPHS];
    int t = threadIdx.x;
    if (t < B_GRAPHS) bins[t] = 0.f;
    __syncthreads();
    int i = blockIdx.x * 256 + t;
    if (i < N_NODES) atomicAdd(&bins[gids[i]], hh[i]);
    __syncthreads();
    if (t < B_GRAPHS && bins[t] != 0.f) atomicAdd(&dout[t], bins[t]);
}

extern "C" void kernel_launch(void* const* d_in, const int* in_sizes, int n_in,
                              void* d_out, int out_size, void* d_ws, size_t ws_size,
                              hipStream_t stream) {
    (void)in_sizes; (void)n_in; (void)out_size; (void)ws_size;
    const float* R      = (const float*)d_in[0];
    const int*   Z      = (const int*)d_in[1];
    const int*   src    = (const int*)d_in[2];
    const int*   dst    = (const int*)d_in[3];
    const int*   gids   = (const int*)d_in[4];
    const float* emb    = (const float*)d_in[5];
    const float* offs   = (const float*)d_in[6];
    const float* widths = (const float*)d_in[7];
    const float* fc_w   = (const float*)d_in[8];
    const float* attn_l = (const float*)d_in[9];
    const float* attn_r = (const float*)d_in[10];
    const float* fw1    = (const float*)d_in[11];
    const float* fb1    = (const float*)d_in[12];
    const float* fw2    = (const float*)d_in[13];
    const float* fb2    = (const float*)d_in[14];
    const float* mw1    = (const float*)d_in[15];
    const float* mb1    = (const float*)d_in[16];
    const float* mw2    = (const float*)d_in[17];
    const float* mb2    = (const float*)d_in[18];
    const float* ow1    = (const float*)d_in[19];
    const float* ob1    = (const float*)d_in[20];
    const float* ow2    = (const float*)d_in[21];
    const float* ob2    = (const float*)d_in[22];

    char* p = (char*)d_ws;
    float* x      = (float*)p; p += (size_t)N_NODES * 64 * 4;
    unsigned int* hq = (unsigned int*)p; p += (size_t)N_NODES * 64 * 4;  // packed bf16 pairs
    float* el     = (float*)p; p += (size_t)N_NODES * 2 * 4;
    float* er     = (float*)p; p += (size_t)N_NODES * 2 * 4;
    float* denom  = (float*)p; p += (size_t)N_NODES * 2 * 4;
    float* agg    = (float*)p; p += (size_t)N_NODES * 128 * 4;
    int2*  surv   = (int2*)p;  p += (size_t)N_EDGES * 8;
    int2*  pk     = (int2*)p;  p += (size_t)N_EDGES * 8;
    float* hh     = (float*)p; p += (size_t)N_NODES * 4;
    int*   bsum   = (int*)p;   p += 1024;
    int*   bpref  = (int*)p;   p += 1024;
    // filter-net LUT aliases pk: 3*2049*128*4 = 3,147,264 B <= 6,400,000 B.
    // pk is dead after repr_scatter; lut is built strictly after it.
    unsigned int* lut = (unsigned int*)pk;
    // scan temporaries aliased into x (x written by repr_embed_h, strictly after
    // repr_scatter in stream order):
    int* count = (int*)x;
    int* excl  = (int*)((char*)x + 256 * 1024);
    int* cur   = (int*)((char*)x + 512 * 1024);

    // one-time prep: zero edge counter + d_out
    repr_prep<<<(N_NODES + B_GRAPHS + 255) / 256, 256, 0, stream>>>(
        count, (float*)d_out);
    repr_hist<<<N_EDGES / 256, 256, 0, stream>>>(R, src, dst, count, pk);
    repr_scanA<<<NCHUNK, 256, 0, stream>>>(count, excl, bsum);
    repr_scanB<<<1, 256, 0, stream>>>(bsum, bpref);
    repr_scanC<<<NCHUNK, 256, 0, stream>>>(excl, bpref, cur);
    repr_scatter<<<N_EDGES / 256, 256, 0, stream>>>(pk, cur, surv);

    // build the w(r)*C(r) tables (pk is dead from here on)
    repr_lut_build<<<L_LAYERS * (LUT_T / LROWS), 256, 0, stream>>>(
        offs, widths, fw1, fb1, fw2, fb2, lut);

    repr_embed_h<<<NBLK, 256, 0, stream>>>(
        emb, Z, fc_w, attn_l, attn_r, x, hq, el, er);

    for (int l = 0; l < L_LAYERS; l++) {
        repr_zero<<<(ZTOT + 255) / 256, 256, 0, stream>>>(agg, denom);
        repr_msg_lut<<<N_EDGES / TILE, 256, 0, stream>>>(
            surv, el, er, hq, lut + (size_t)l * LUT_ROWS * HD, agg, denom);
        if (l < L_LAYERS - 1) {
            repr_mlp_h<<<NBLK, 256, 0, stream>>>(
                agg, denom, mw1 + (size_t)l * 128 * 64, mb1 + l * 64,
                mw2 + (size_t)l * 64 * 64, mb2 + l * 64,
                fc_w + (size_t)(l + 1) * 64 * 128, attn_l + (l + 1) * 128,
                attn_r + (l + 1) * 128, x, hq, el, er);
        } else {
            repr_mlp_out<<<NBLK, 256, 0, stream>>>(
                agg, denom, mw1 + (size_t)l * 128 * 64, mb1 + l * 64,
                mw2 + (size_t)l * 64 * 64, mb2 + l * 64,
                ow1, ob1, ow2, ob2, x, hh);
        }
    }
    repr_gsum<<<NCHUNK, 256, 0, stream>>>(hh, gids, (float*)d_out);
}

// Round 13
// 576.425 us; speedup vs baseline: 3.6737x; 1.0833x over previous
//
#include <hip/hip_runtime.h>
#include <stdint.h>

#define N_NODES 50000
#define N_EDGES 800000
#define B_GRAPHS 64
#define D_DIM 64
#define HD 128
#define G_GAUSS 50
#define HID_DIM 128
#define L_LAYERS 3
#define LN2 0.69314718055994530942f
#define PI_OVER_8 0.39269908169872414f
#define NCHUNK 196            // ceil(50000/256)

#define TN 64                 // nodes per node-GEMM block
#define TLD 132               // fp32 LDS leading dim for 128-wide tiles
#define XLD 68                // fp32 LDS leading dim for 64-wide tiles
#define NBLK ((N_NODES + TN - 1) / TN)   // 782

// filter-net lookup table: w(r)*C(r) over r in [0,8), linear interpolation.
// Rows 0..LUT_T-1 cover [0,8); row LUT_T is all-zero (r>=8 cutoff folded in).
#define LUT_T 2048
#define LUT_ROWS (LUT_T + 1)
#define LROWS 8               // table rows built per block

__device__ __forceinline__ float sspf(float x) {
    float ax = fabsf(x);
    return fmaxf(x, 0.f) + __logf(1.f + __expf(-ax)) - LN2;
}
__device__ __forceinline__ unsigned short f2bf(float f) {
    union { float f; unsigned int i; } v; v.f = f;
    unsigned int u = v.i;
    return (unsigned short)((u + 0x7FFFu + ((u >> 16) & 1u)) >> 16);
}

// ------------- one-time: zero edge counter + output -------------
__global__ void repr_prep(int* __restrict__ count, float* __restrict__ dout) {
    int i = blockIdx.x * 256 + threadIdx.x;
    if (i < N_NODES) count[i] = 0;
    else if (i < N_NODES + B_GRAPHS) dout[i - N_NODES] = 0.f;
}

// ------------- per-layer: zero denom fully + agg rows of atomic-target dsts ------
// Atomic flushes in repr_msg_lut hit only dsts of the first/last edge of each
// 64-edge subrange (25000 fixed positions). Interior rows are plain-stored
// (overwritten), degree-0 rows are neutralized by inv=0 in load_ssp_agg.
#define NSUB (N_EDGES / 64)            // 12500 subranges
#define ZB_T (2 * N_NODES / 4 + 2 * NSUB * 32)   // 25000 + 800000 threads
__global__ void repr_zero_b(const int2* __restrict__ surv,
                            float* __restrict__ agg, float* __restrict__ denom) {
    int i = blockIdx.x * 256 + threadIdx.x;
    float4 z = make_float4(0.f, 0.f, 0.f, 0.f);
    if (i < 2 * N_NODES / 4) {
        ((float4*)denom)[i] = z;
    } else {
        int j = i - 2 * N_NODES / 4;
        if (j >= 2 * NSUB * 32) return;
        int row = j >> 5, c4 = j & 31;
        int sr = row >> 1;
        int p = sr * 64 + ((row & 1) ? 63 : 0);
        int d = (int)((unsigned)surv[p].x >> 16);
        *(float4*)&agg[(size_t)d * HD + c4 * 4] = z;
    }
}

// ------------- one-time: build wc(r) = (ssp(gs@W1+b1)@W2 + b2) * C(r) table -------------
// interleaved bf16: lut[l][i][c] = bf16(wc[i][c]) | bf16(wc[i+1][c])<<16
__global__ __launch_bounds__(256) void repr_lut_build(
    const float* __restrict__ offs, const float* __restrict__ widths,
    const float* __restrict__ fw1, const float* __restrict__ fb1,
    const float* __restrict__ fw2, const float* __restrict__ fb2,
    unsigned int* __restrict__ lut)
{
    __shared__ float gs_s[LROWS + 1][G_GAUSS];
    __shared__ float hid_s[LROWS + 1][HID_DIM];
    __shared__ float wc_s[LROWS + 1][HD];
    const int nb = LUT_T / LROWS;            // 256 blocks per layer
    int l = blockIdx.x / nb;
    int i0r = (blockIdx.x % nb) * LROWS;
    int tid = threadIdx.x;
    const float step = 8.0f / LUT_T;

    for (int j = tid; j < (LROWS + 1) * G_GAUSS; j += 256) {
        int r = j / G_GAUSS, k = j - r * G_GAUSS;
        float rr = (i0r + r) * step;
        float wdt = widths[k];
        float dr = rr - offs[k];
        gs_s[r][k] = expf(-0.5f / (wdt * wdt) * dr * dr);
    }
    __syncthreads();

    int c = tid & 127, sub = tid >> 7;
    int rlo = sub * 4;                       // rows 0..4 / 4..8 (row 4 dup, benign)
    {
        const float* W1 = fw1 + (size_t)l * G_GAUSS * HID_DIM + c;
        float acc[5];
        float bb = fb1[l * HID_DIM + c];
        #pragma unroll
        for (int r = 0; r < 5; r++) acc[r] = bb;
        for (int k = 0; k < G_GAUSS; k++) {
            float wv = W1[k * HID_DIM];
            #pragma unroll
            for (int r = 0; r < 5; r++)
                acc[r] = fmaf(gs_s[rlo + r][k], wv, acc[r]);
        }
        #pragma unroll
        for (int r = 0; r < 5; r++) hid_s[rlo + r][c] = sspf(acc[r]);
    }
    __syncthreads();
    {
        const float* W2 = fw2 + (size_t)l * HID_DIM * HD + c;
        float acc[5];
        float bb = fb2[l * HD + c];
        #pragma unroll
        for (int r = 0; r < 5; r++) acc[r] = bb;
        for (int k = 0; k < HID_DIM; k++) {
            float wv = W2[k * HD];
            #pragma unroll
            for (int r = 0; r < 5; r++)
                acc[r] = fmaf(hid_s[rlo + r][k], wv, acc[r]);
        }
        #pragma unroll
        for (int r = 0; r < 5; r++) {
            float rr = (i0r + rlo + r) * step;
            float C = (rr < 8.0f) ? 0.5f * (cosf(rr * PI_OVER_8) + 1.f) : 0.f;
            wc_s[rlo + r][c] = acc[r] * C;
        }
    }
    __syncthreads();
    for (int j = tid; j < LROWS * HD; j += 256) {
        int r = j >> 7, cc = j & 127;
        unsigned int lo = f2bf(wc_s[r][cc]);
        unsigned int hi = f2bf(wc_s[r + 1][cc]);
        lut[((size_t)l * LUT_ROWS + i0r + r) * HD + cc] = lo | (hi << 16);
    }
    // last block of each layer writes the zeros row (r >= 8 cutoff)
    if (i0r == LUT_T - LROWS && tid < HD)
        lut[((size_t)l * LUT_ROWS + LUT_T) * HD + tid] = 0u;
}

// ------------- histogram + rank + pack {src|dst<<16, r fixed-point} per edge ------
// rank[e] = this edge's arrival index among edges with the same dst -- reuses
// the histogram atomic's return value, so repr_scatter needs NO atomics.
__global__ void repr_hist(const float* __restrict__ R,
                          const int* __restrict__ src, const int* __restrict__ dst,
                          int* __restrict__ count,
                          int2* __restrict__ pk, unsigned short* __restrict__ rank) {
    int e = blockIdx.x * blockDim.x + threadIdx.x;
    if (e >= N_EDGES) return;
    int s = src[e], d = dst[e];
    float dx = R[3*s+0] - R[3*d+0];
    float dy = R[3*s+1] - R[3*d+1];
    float dz = R[3*s+2] - R[3*d+2];
    float r = sqrtf(dx*dx + dy*dy + dz*dz);
    // r*2^24; i0 = rf>>16 in [0,2047] for r<8, else 2048 -> zeros row
    unsigned rf = (r < 8.0f) ? (unsigned)(r * 16777216.f) : (2048u << 16);
    if (rf > (2048u << 16)) rf = 2048u << 16;
    pk[e] = make_int2((int)((unsigned)s | ((unsigned)d << 16)), (int)rf);
    int rnk = atomicAdd(&count[d], 1);
    rank[e] = (unsigned short)rnk;
}

// ------------- 2-level exclusive scan over 50000 counts -> rowptr -------------
__global__ void repr_scanA(const int* __restrict__ cnt, int* __restrict__ excl,
                           int* __restrict__ bsum) {
    __shared__ int tmp[256];
    int t = threadIdx.x, b = blockIdx.x;
    int i = b * 256 + t;
    int v = (i < N_NODES) ? cnt[i] : 0;
    tmp[t] = v; __syncthreads();
    for (int off = 1; off < 256; off <<= 1) {
        int add = (t >= off) ? tmp[t - off] : 0;
        __syncthreads();
        tmp[t] += add;
        __syncthreads();
    }
    if (i < N_NODES) excl[i] = tmp[t] - v;
    if (t == 255) bsum[b] = tmp[255];
}
__global__ void repr_scanB(const int* __restrict__ bsum, int* __restrict__ bpref) {
    __shared__ int tmp[256];
    int t = threadIdx.x;
    int v = (t < NCHUNK) ? bsum[t] : 0;
    tmp[t] = v; __syncthreads();
    for (int off = 1; off < 256; off <<= 1) {
        int add = (t >= off) ? tmp[t - off] : 0;
        __syncthreads();
        tmp[t] += add;
        __syncthreads();
    }
    if (t < NCHUNK) bpref[t] = tmp[t] - v;
}
__global__ void repr_scanC(const int* __restrict__ excl, const int* __restrict__ bpref,
                           int* __restrict__ rowptr) {
    int i = blockIdx.x * 256 + threadIdx.x;
    if (i < N_NODES) rowptr[i] = excl[i] + bpref[blockIdx.x];
}

// ------------- scatter: rank-addressed, atomic-free; one 8B store per edge -------
__global__ void repr_scatter(const int2* __restrict__ pk,
                             const unsigned short* __restrict__ rank,
                             const int* __restrict__ rowptr,
                             int2* __restrict__ surv) {
    int e = blockIdx.x * blockDim.x + threadIdx.x;
    if (e >= N_EDGES) return;
    int2 v = pk[e];
    int d = (int)((unsigned)v.x >> 16);
    surv[rowptr[d] + (int)rank[e]] = v;
}

// ================= tiled fp32 node GEMMs (64 nodes / block, 256 threads) =================

// agg holds UNNORMALIZED weighted sums; divide by denom[d] here (deferred softmax).
__device__ __forceinline__ void load_ssp_agg(int base, int tid,
        const float* __restrict__ agg, const float* __restrict__ denom,
        float* __restrict__ bufA) {
    int row = tid >> 2;
    int c0 = (tid & 3) << 5;
    int n = base + row;
    float2 dn = *(const float2*)&denom[2 * (size_t)n];
    float i0v = dn.x > 0.f ? 1.f / dn.x : 0.f;
    float i1v = dn.y > 0.f ? 1.f / dn.y : 0.f;
    float inv = (c0 < 64) ? i0v : i1v;
    const float* ap = agg + (size_t)n * HD + c0;
    float* tp = bufA + row * TLD + c0;
    #pragma unroll
    for (int j = 0; j < 8; j++) {
        float4 v = *(const float4*)(ap + j * 4);
        tp[j*4+0] = sspf(v.x * inv); tp[j*4+1] = sspf(v.y * inv);
        tp[j*4+2] = sspf(v.z * inv); tp[j*4+3] = sspf(v.w * inv);
    }
}

__device__ __forceinline__ void gemm_mlp(int base, int tid,
        const float* __restrict__ w1, const float* __restrict__ b1,
        const float* __restrict__ w2, const float* __restrict__ b2,
        float* __restrict__ x, float* __restrict__ bufA, float* __restrict__ v1s)
{
    const int rg = tid >> 4, cg = tid & 15;
    const int r0 = rg * 4, c0 = cg * 4;
    float acc[4][4];
    #pragma unroll
    for (int r = 0; r < 4; r++)
        #pragma unroll
        for (int c = 0; c < 4; c++) acc[r][c] = 0.f;
    for (int k0 = 0; k0 < 128; k0 += 4) {
        float av[4][4];
        #pragma unroll
        for (int r = 0; r < 4; r++)
            *(float4*)av[r] = *(const float4*)&bufA[(r0 + r) * TLD + k0];
        #pragma unroll
        for (int kk = 0; kk < 4; kk++) {
            float4 wv = *(const float4*)(w1 + (k0 + kk) * 64 + c0);
            float wf[4] = {wv.x, wv.y, wv.z, wv.w};
            #pragma unroll
            for (int r = 0; r < 4; r++)
                #pragma unroll
                for (int c = 0; c < 4; c++)
                    acc[r][c] = fmaf(av[r][kk], wf[c], acc[r][c]);
        }
    }
    {
        float4 bv = *(const float4*)(b1 + c0);
        float ba[4] = {bv.x, bv.y, bv.z, bv.w};
        #pragma unroll
        for (int r = 0; r < 4; r++)
            #pragma unroll
            for (int c = 0; c < 4; c++)
                v1s[(r0 + r) * XLD + c0 + c] = sspf(acc[r][c] + ba[c]);
    }
    __syncthreads();
    float acc2[4][4];
    #pragma unroll
    for (int r = 0; r < 4; r++)
        #pragma unroll
        for (int c = 0; c < 4; c++) acc2[r][c] = 0.f;
    for (int k0 = 0; k0 < 64; k0 += 4) {
        float av[4][4];
        #pragma unroll
        for (int r = 0; r < 4; r++)
            *(float4*)av[r] = *(const float4*)&v1s[(r0 + r) * XLD + k0];
        #pragma unroll
        for (int kk = 0; kk < 4; kk++) {
            float4 wv = *(const float4*)(w2 + (k0 + kk) * 64 + c0);
            float wf[4] = {wv.x, wv.y, wv.z, wv.w};
            #pragma unroll
            for (int r = 0; r < 4; r++)
                #pragma unroll
                for (int c = 0; c < 4; c++)
                    acc2[r][c] = fmaf(av[r][kk], wf[c], acc2[r][c]);
        }
    }
    {
        float4 bv = *(const float4*)(b2 + c0);
        #pragma unroll
        for (int r = 0; r < 4; r++) {
            int n = base + r0 + r;
            float4 xv = *(const float4*)(x + (size_t)n * 64 + c0);
            float4 o;
            o.x = acc2[r][0] + bv.x + xv.x;
            o.y = acc2[r][1] + bv.y + xv.y;
            o.z = acc2[r][2] + bv.z + xv.z;
            o.w = acc2[r][3] + bv.w + xv.w;
            *(float4*)&bufA[(r0 + r) * XLD + c0] = o;
            if (n < N_NODES) *(float4*)(x + (size_t)n * 64 + c0) = o;
        }
    }
    __syncthreads();
}

// h stored packed bf16: hq[n*64 + c/2] = bf16(h[c]) | bf16(h[c+1])<<16
__device__ __forceinline__ void gemm_h(int base, int tid,
        const float* __restrict__ bufA,
        const float* __restrict__ fc_w, const float* __restrict__ attn_l,
        const float* __restrict__ attn_r,
        unsigned int* __restrict__ hq, float* __restrict__ el, float* __restrict__ er)
{
    const int rg = tid >> 4, cg = tid & 15;
    const int r0 = rg * 4, c0 = cg * 8;
    float acc[4][8];
    #pragma unroll
    for (int r = 0; r < 4; r++)
        #pragma unroll
        for (int c = 0; c < 8; c++) acc[r][c] = 0.f;
    for (int k0 = 0; k0 < 64; k0 += 4) {
        float av[4][4];
        #pragma unroll
        for (int r = 0; r < 4; r++)
            *(float4*)av[r] = *(const float4*)&bufA[(r0 + r) * XLD + k0];
        #pragma unroll
        for (int kk = 0; kk < 4; kk++) {
            float4 w0 = *(const float4*)(fc_w + (k0 + kk) * 128 + c0);
            float4 w1v = *(const float4*)(fc_w + (k0 + kk) * 128 + c0 + 4);
            float wf[8] = {w0.x, w0.y, w0.z, w0.w, w1v.x, w1v.y, w1v.z, w1v.w};
            #pragma unroll
            for (int r = 0; r < 4; r++)
                #pragma unroll
                for (int c = 0; c < 8; c++)
                    acc[r][c] = fmaf(av[r][kk], wf[c], acc[r][c]);
        }
    }
    float al[8], ar[8];
    #pragma unroll
    for (int c = 0; c < 8; c++) { al[c] = attn_l[c0 + c]; ar[c] = attn_r[c0 + c]; }
    int head = cg >> 3;
    #pragma unroll
    for (int r = 0; r < 4; r++) {
        int n = base + r0 + r;
        float pel = 0.f, per = 0.f;
        #pragma unroll
        for (int c = 0; c < 8; c++) {
            pel = fmaf(acc[r][c], al[c], pel);
            per = fmaf(acc[r][c], ar[c], per);
        }
        if (n < N_NODES) {
            uint4 pv;
            pv.x = (unsigned int)f2bf(acc[r][0]) | ((unsigned int)f2bf(acc[r][1]) << 16);
            pv.y = (unsigned int)f2bf(acc[r][2]) | ((unsigned int)f2bf(acc[r][3]) << 16);
            pv.z = (unsigned int)f2bf(acc[r][4]) | ((unsigned int)f2bf(acc[r][5]) << 16);
            pv.w = (unsigned int)f2bf(acc[r][6]) | ((unsigned int)f2bf(acc[r][7]) << 16);
            *(uint4*)(hq + (size_t)n * 64 + cg * 4) = pv;
        }
        #pragma unroll
        for (int off = 1; off < 8; off <<= 1) {
            pel += __shfl_xor(pel, off, 64);
            per += __shfl_xor(per, off, 64);
        }
        if ((cg & 7) == 0 && n < N_NODES) {
            el[n * 2 + head] = pel;
            er[n * 2 + head] = per;
        }
    }
}

__global__ __launch_bounds__(256) void repr_embed_h(
        const float* __restrict__ emb, const int* __restrict__ Z,
        const float* __restrict__ fc_w, const float* __restrict__ attn_l,
        const float* __restrict__ attn_r,
        float* __restrict__ x, unsigned int* __restrict__ hq,
        float* __restrict__ el, float* __restrict__ er) {
    __shared__ float bufA[TN * XLD];
    int base = blockIdx.x * TN, tid = threadIdx.x;
    int row = tid >> 2;
    int c0 = (tid & 3) << 4;
    int n = base + row;
    int z = (n < N_NODES) ? Z[n] : 0;
    const float* ep = emb + (size_t)z * D_DIM + c0;
    float* bp = bufA + row * XLD + c0;
    #pragma unroll
    for (int j = 0; j < 4; j++) {
        float4 v = *(const float4*)(ep + j * 4);
        *(float4*)(bp + j * 4) = v;
        if (n < N_NODES) *(float4*)(x + (size_t)n * D_DIM + c0 + j * 4) = v;
    }
    __syncthreads();
    gemm_h(base, tid, bufA, fc_w, attn_l, attn_r, hq, el, er);
}

__global__ __launch_bounds__(256) void repr_mlp_h(
        const float* __restrict__ agg, const float* __restrict__ denom,
        const float* __restrict__ w1, const float* __restrict__ b1,
        const float* __restrict__ w2, const float* __restrict__ b2,
        const float* __restrict__ fc_w, const float* __restrict__ attn_l,
        const float* __restrict__ attn_r,
        float* __restrict__ x, unsigned int* __restrict__ hq,
        float* __restrict__ el, float* __restrict__ er) {
    __shared__ float bufA[TN * TLD];
    __shared__ float v1s[TN * XLD];
    int base = blockIdx.x * TN, tid = threadIdx.x;
    load_ssp_agg(base, tid, agg, denom, bufA);
    __syncthreads();
    gemm_mlp(base, tid, w1, b1, w2, b2, x, bufA, v1s);
    gemm_h(base, tid, bufA, fc_w, attn_l, attn_r, hq, el, er);
}

__global__ __launch_bounds__(256) void repr_mlp_out(
        const float* __restrict__ agg, const float* __restrict__ denom,
        const float* __restrict__ w1, const float* __restrict__ b1,
        const float* __restrict__ w2, const float* __restrict__ b2,
        const float* __restrict__ ow1, const float* __restrict__ ob1,
        const float* __restrict__ ow2, const float* __restrict__ ob2,
        float* __restrict__ x, float* __restrict__ hh) {
    __shared__ float bufA[TN * TLD];
    __shared__ float v1s[TN * XLD];
    int base = blockIdx.x * TN, tid = threadIdx.x;
    load_ssp_agg(base, tid, agg, denom, bufA);
    __syncthreads();
    gemm_mlp(base, tid, w1, b1, w2, b2, x, bufA, v1s);
    const int rg = tid >> 4, cg = tid & 15;
    const int r0 = rg * 4, c0 = cg * 8;
    float acc[4][8];
    #pragma unroll
    for (int r = 0; r < 4; r++)
        #pragma unroll
        for (int c = 0; c < 8; c++) acc[r][c] = 0.f;
    for (int k0 = 0; k0 < 64; k0 += 4) {
        float av[4][4];
        #pragma unroll
        for (int r = 0; r < 4; r++)
            *(float4*)av[r] = *(const float4*)&bufA[(r0 + r) * XLD + k0];
        #pragma unroll
        for (int kk = 0; kk < 4; kk++) {
            float4 w0 = *(const float4*)(ow1 + (k0 + kk) * 128 + c0);
            float4 w1v = *(const float4*)(ow1 + (k0 + kk) * 128 + c0 + 4);
            float wf[8] = {w0.x, w0.y, w0.z, w0.w, w1v.x, w1v.y, w1v.z, w1v.w};
            #pragma unroll
            for (int r = 0; r < 4; r++)
                #pragma unroll
                for (int c = 0; c < 8; c++)
                    acc[r][c] = fmaf(av[r][kk], wf[c], acc[r][c]);
        }
    }
    float o1[8], w2c[8];
    #pragma unroll
    for (int c = 0; c < 8; c++) { o1[c] = ob1[c0 + c]; w2c[c] = ow2[c0 + c]; }
    #pragma unroll
    for (int r = 0; r < 4; r++) {
        int n = base + r0 + r;
        float s = 0.f;
        #pragma unroll
        for (int c = 0; c < 8; c++)
            s = fmaf(sspf(acc[r][c] + o1[c]), w2c[c], s);
        #pragma unroll
        for (int off = 1; off < 16; off <<= 1)
            s += __shfl_xor(s, off, 64);
        if (cg == 0 && n < N_NODES) hh[n] = s + ob2[0];
    }
}

// ------------- LUT message + UNNORMALIZED segmented reduce + denom fusion ----------
// TILE=256 edges (800000/256 = 3125 tiles, exact); 256 threads =
// 64 col-pairs x 4 row-subranges of 64 edges. All 800k edges (r>=8 hits the
// zeros LUT row -> 0 into agg, exp feeds denom).
// Denominator: segment-head lanes (LDS-detected, works across wave boundary)
// sum staged exps per dst-run, one global atomicAdd pair per (segment, tile).
// agg flushes: interior segments plain-store; subrange/tile boundaries atomic
// (boundary rows pre-zeroed by repr_zero_b).
#define TILE 256
__global__ __launch_bounds__(256) void repr_msg_lut(
    const int2* __restrict__ surv,
    const float* __restrict__ el, const float* __restrict__ er,
    const unsigned int* __restrict__ hq,
    const unsigned int* __restrict__ lut,
    float* __restrict__ agg, float* __restrict__ denom)
{
    __shared__ int4 rowinfo[TILE];     // {lut row i0, src, dst, frac bits}
    __shared__ float scl[TILE][2];     // exp(leaky(el+er)) per head
    int base = blockIdx.x * TILE;
    int tid = threadIdx.x;
    int d_own; float e0, e1;
    {
        int2 ev = surv[base + tid];
        int sn = (int)((unsigned)ev.x & 0xFFFFu);
        d_own  = (int)((unsigned)ev.x >> 16);
        unsigned rf = (unsigned)ev.y;
        int i0 = (int)(rf >> 16);
        float fr = (float)(rf & 0xFFFFu) * (1.f / 65536.f);
        float2 a = *(const float2*)&el[2 * sn];
        float2 b = *(const float2*)&er[2 * d_own];
        float v0 = a.x + b.x; v0 = v0 >= 0.f ? v0 : 0.2f * v0;
        float v1 = a.y + b.y; v1 = v1 >= 0.f ? v1 : 0.2f * v1;
        e0 = __expf(v0); e1 = __expf(v1);
        rowinfo[tid] = make_int4(i0, sn, d_own, __float_as_int(fr));
        scl[tid][0] = e0; scl[tid][1] = e1;
    }
    __syncthreads();
    // segment-head lanes accumulate this tile's denom contribution
    {
        bool headl = (tid == 0) || (rowinfo[tid - 1].z != d_own);
        if (headl) {
            float s0 = e0, s1 = e1;
            for (int r = tid + 1; r < TILE; r++) {
                if (rowinfo[r].z != d_own) break;
                s0 += scl[r][0]; s1 += scl[r][1];
            }
            atomicAdd(&denom[2 * d_own], s0);
            atomicAdd(&denom[2 * d_own + 1], s1);
        }
    }
    const int cp = tid & 63;           // col pair: cols 2cp, 2cp+1
    const int sp = tid >> 6;           // row-subrange: rows [sp*64, sp*64+64)
    const int head = cp >> 5;          // cols 0-63 head0, 64-127 head1
    const int lo = sp * 64;
    const uint2* __restrict__ l2p = (const uint2*)lut;
    float sum0 = 0.f, sum1 = 0.f;
    int cur_d = -1;
    int seg_first = 1;                 // current segment started at subrange begin
    #pragma unroll 4
    for (int j = 0; j < 64; j++) {
        int r = lo + j;
        int4 ri = rowinfo[r];          // wave-uniform LDS broadcast
        if (ri.z != cur_d) {
            if (cur_d >= 0) {
                float* ap = &agg[(size_t)cur_d * HD + 2 * cp];
                // segment possibly extends into previous subrange/block -> atomic
                if (seg_first) { atomicAdd(ap, sum0); atomicAdd(ap + 1, sum1); }
                else *(float2*)ap = make_float2(sum0, sum1);
            }
            cur_d = ri.z; sum0 = 0.f; sum1 = 0.f; seg_first = (j == 0);
        }
        uint2 tv = l2p[(size_t)ri.x * 64 + cp];
        float fr = __int_as_float(ri.w);
        float wa0 = __uint_as_float(tv.x << 16);
        float wa1 = __uint_as_float(tv.x & 0xFFFF0000u);
        float wb0 = __uint_as_float(tv.y << 16);
        float wb1 = __uint_as_float(tv.y & 0xFFFF0000u);
        unsigned int hv = hq[(size_t)ri.y * 64 + cp];
        float ha = __uint_as_float(hv << 16);
        float hb = __uint_as_float(hv & 0xFFFF0000u);
        float s = scl[r][head];
        float wa = fmaf(fr, wa1 - wa0, wa0);
        float wb = fmaf(fr, wb1 - wb0, wb0);
        sum0 = fmaf(wa * ha, s, sum0);
        sum1 = fmaf(wb * hb, s, sum1);
    }
    // trailing segment may continue into next subrange/block -> atomic
    if (cur_d >= 0) {
        float* ap = &agg[(size_t)cur_d * HD + 2 * cp];
        atomicAdd(ap, sum0); atomicAdd(ap + 1, sum1);
    }
}

// ------------- graph segment-sum with LDS privatization -> d_out directly -------------
__global__ void repr_gsum(const float* __restrict__ hh, const int* __restrict__ gids,
                          float* __restrict__ dout) {
    __shared__ float bins[B_GRAPHS];
    int t = threadIdx.x;
    if (t < B_GRAPHS) bins[t] = 0.f;
    __syncthreads();
    int i = blockIdx.x * 256 + t;
    if (i < N_NODES) atomicAdd(&bins[gids[i]], hh[i]);
    __syncthreads();
    if (t < B_GRAPHS && bins[t] != 0.f) atomicAdd(&dout[t], bins[t]);
}

extern "C" void kernel_launch(void* const* d_in, const int* in_sizes, int n_in,
                              void* d_out, int out_size, void* d_ws, size_t ws_size,
                              hipStream_t stream) {
    (void)in_sizes; (void)n_in; (void)out_size; (void)ws_size;
    const float* R      = (const float*)d_in[0];
    const int*   Z      = (const int*)d_in[1];
    const int*   src    = (const int*)d_in[2];
    const int*   dst    = (const int*)d_in[3];
    const int*   gids   = (const int*)d_in[4];
    const float* emb    = (const float*)d_in[5];
    const float* offs   = (const float*)d_in[6];
    const float* widths = (const float*)d_in[7];
    const float* fc_w   = (const float*)d_in[8];
    const float* attn_l = (const float*)d_in[9];
    const float* attn_r = (const float*)d_in[10];
    const float* fw1    = (const float*)d_in[11];
    const float* fb1    = (const float*)d_in[12];
    const float* fw2    = (const float*)d_in[13];
    const float* fb2    = (const float*)d_in[14];
    const float* mw1    = (const float*)d_in[15];
    const float* mb1    = (const float*)d_in[16];
    const float* mw2    = (const float*)d_in[17];
    const float* mb2    = (const float*)d_in[18];
    const float* ow1    = (const float*)d_in[19];
    const float* ob1    = (const float*)d_in[20];
    const float* ow2    = (const float*)d_in[21];
    const float* ob2    = (const float*)d_in[22];

    char* p = (char*)d_ws;
    float* x      = (float*)p; p += (size_t)N_NODES * 64 * 4;
    unsigned int* hq = (unsigned int*)p; p += (size_t)N_NODES * 64 * 4;  // packed bf16 pairs
    float* el     = (float*)p; p += (size_t)N_NODES * 2 * 4;
    float* er     = (float*)p; p += (size_t)N_NODES * 2 * 4;
    float* denom  = (float*)p; p += (size_t)N_NODES * 2 * 4;
    float* agg    = (float*)p; p += (size_t)N_NODES * 128 * 4;
    int2*  surv   = (int2*)p;  p += (size_t)N_EDGES * 8;
    int2*  pk     = (int2*)p;  p += (size_t)N_EDGES * 8;
    float* hh     = (float*)p; p += (size_t)N_NODES * 4;
    int*   bsum   = (int*)p;   p += 1024;
    int*   bpref  = (int*)p;   p += 1024;
    // filter-net LUT aliases pk: 3*2049*128*4 = 3,147,264 B <= 6,400,000 B.
    // pk is dead after repr_scatter; lut is built strictly after it.
    unsigned int* lut = (unsigned int*)pk;
    // scan/scatter temporaries aliased into x (x written by repr_embed_h, strictly
    // after repr_scatter in stream order):
    int* count = (int*)x;                                        // 200 KB
    int* excl  = (int*)((char*)x + 256 * 1024);                  // 200 KB
    unsigned short* rank = (unsigned short*)((char*)x + 512 * 1024);   // 1.6 MB
    int* rowptr = (int*)((char*)x + 2560 * 1024);                // 200 KB

    // one-time prep: zero edge counter + d_out
    repr_prep<<<(N_NODES + B_GRAPHS + 255) / 256, 256, 0, stream>>>(
        count, (float*)d_out);
    repr_hist<<<N_EDGES / 256, 256, 0, stream>>>(R, src, dst, count, pk, rank);
    repr_scanA<<<NCHUNK, 256, 0, stream>>>(count, excl, bsum);
    repr_scanB<<<1, 256, 0, stream>>>(bsum, bpref);
    repr_scanC<<<NCHUNK, 256, 0, stream>>>(excl, bpref, rowptr);
    repr_scatter<<<N_EDGES / 256, 256, 0, stream>>>(pk, rank, rowptr, surv);

    // build the w(r)*C(r) tables (pk is dead from here on)
    repr_lut_build<<<L_LAYERS * (LUT_T / LROWS), 256, 0, stream>>>(
        offs, widths, fw1, fb1, fw2, fb2, lut);

    repr_embed_h<<<NBLK, 256, 0, stream>>>(
        emb, Z, fc_w, attn_l, attn_r, x, hq, el, er);

    for (int l = 0; l < L_LAYERS; l++) {
        repr_zero_b<<<(ZB_T + 255) / 256, 256, 0, stream>>>(surv, agg, denom);
        repr_msg_lut<<<N_EDGES / TILE, 256, 0, stream>>>(
            surv, el, er, hq, lut + (size_t)l * LUT_ROWS * HD, agg, denom);
        if (l < L_LAYERS - 1) {
            repr_mlp_h<<<NBLK, 256, 0, stream>>>(
                agg, denom, mw1 + (size_t)l * 128 * 64, mb1 + l * 64,
                mw2 + (size_t)l * 64 * 64, mb2 + l * 64,
                fc_w + (size_t)(l + 1) * 64 * 128, attn_l + (l + 1) * 128,
                attn_r + (l + 1) * 128, x, hq, el, er);
        } else {
            repr_mlp_out<<<NBLK, 256, 0, stream>>>(
                agg, denom, mw1 + (size_t)l * 128 * 64, mb1 + l * 64,
                mw2 + (size_t)l * 64 * 64, mb2 + l * 64,
                ow1, ob1, ow2, ob2, x, hh);
        }
    }
    repr_gsum<<<NCHUNK, 256, 0, stream>>>(hh, gids, (float*)d_out);
}

// Round 14
// 552.483 us; speedup vs baseline: 3.8330x; 1.0433x over previous
//
#include <hip/hip_runtime.h>
#include <stdint.h>

#define N_NODES 50000
#define N_EDGES 800000
#define B_GRAPHS 64
#define D_DIM 64
#define HD 128
#define G_GAUSS 50
#define HID_DIM 128
#define L_LAYERS 3
#define LN2 0.69314718055994530942f
#define PI_OVER_8 0.39269908169872414f
#define NCHUNK 196            // ceil(50000/256)

#define TN 64                 // nodes per node-GEMM block
#define TLD 132               // fp32 LDS leading dim for 128-wide tiles
#define XLD 68                // fp32 LDS leading dim for 64-wide tiles
#define NBLK ((N_NODES + TN - 1) / TN)   // 782

// filter-net lookup table: w(r)*C(r) over r in [0,8), linear interpolation.
// Rows 0..LUT_T-1 cover [0,8); row LUT_T is all-zero (r>=8 cutoff folded in).
#define LUT_T 2048
#define LUT_ROWS (LUT_T + 1)
#define LROWS 8               // table rows built per block

__device__ __forceinline__ float sspf(float x) {
    float ax = fabsf(x);
    return fmaxf(x, 0.f) + __logf(1.f + __expf(-ax)) - LN2;
}
__device__ __forceinline__ unsigned short f2bf(float f) {
    union { float f; unsigned int i; } v; v.f = f;
    unsigned int u = v.i;
    return (unsigned short)((u + 0x7FFFu + ((u >> 16) & 1u)) >> 16);
}

// ------------- one-time: zero edge counter + output -------------
__global__ void repr_prep(int* __restrict__ count, float* __restrict__ dout) {
    int i = blockIdx.x * 256 + threadIdx.x;
    if (i < N_NODES) count[i] = 0;
    else if (i < N_NODES + B_GRAPHS) dout[i - N_NODES] = 0.f;
}

// ------------- per-layer: zero denom fully + agg rows of atomic-target dsts ------
// Atomic flushes in repr_msg_lut hit only dsts of the first/last edge of each
// 64-edge subrange (25000 fixed positions). Interior rows are plain-stored
// (overwritten), degree-0 rows are neutralized by inv=0 in load_ssp_agg.
#define NSUB (N_EDGES / 64)            // 12500 subranges
#define ZB_T (2 * N_NODES / 4 + 2 * NSUB * 32)   // 25000 + 800000 threads
__global__ void repr_zero_b(const int2* __restrict__ surv,
                            float* __restrict__ agg, float* __restrict__ denom) {
    int i = blockIdx.x * 256 + threadIdx.x;
    float4 z = make_float4(0.f, 0.f, 0.f, 0.f);
    if (i < 2 * N_NODES / 4) {
        ((float4*)denom)[i] = z;
    } else {
        int j = i - 2 * N_NODES / 4;
        if (j >= 2 * NSUB * 32) return;
        int row = j >> 5, c4 = j & 31;
        int sr = row >> 1;
        int p = sr * 64 + ((row & 1) ? 63 : 0);
        int d = (int)((unsigned)surv[p].x >> 16);
        *(float4*)&agg[(size_t)d * HD + c4 * 4] = z;
    }
}

// ------------- one-time: build wc(r) = (ssp(gs@W1+b1)@W2 + b2) * C(r) table -------------
// interleaved bf16: lut[l][i][c] = bf16(wc[i][c]) | bf16(wc[i+1][c])<<16
__global__ __launch_bounds__(256) void repr_lut_build(
    const float* __restrict__ offs, const float* __restrict__ widths,
    const float* __restrict__ fw1, const float* __restrict__ fb1,
    const float* __restrict__ fw2, const float* __restrict__ fb2,
    unsigned int* __restrict__ lut)
{
    __shared__ float gs_s[LROWS + 1][G_GAUSS];
    __shared__ float hid_s[LROWS + 1][HID_DIM];
    __shared__ float wc_s[LROWS + 1][HD];
    const int nb = LUT_T / LROWS;            // 256 blocks per layer
    int l = blockIdx.x / nb;
    int i0r = (blockIdx.x % nb) * LROWS;
    int tid = threadIdx.x;
    const float step = 8.0f / LUT_T;

    for (int j = tid; j < (LROWS + 1) * G_GAUSS; j += 256) {
        int r = j / G_GAUSS, k = j - r * G_GAUSS;
        float rr = (i0r + r) * step;
        float wdt = widths[k];
        float dr = rr - offs[k];
        gs_s[r][k] = expf(-0.5f / (wdt * wdt) * dr * dr);
    }
    __syncthreads();

    int c = tid & 127, sub = tid >> 7;
    int rlo = sub * 4;                       // rows 0..4 / 4..8 (row 4 dup, benign)
    {
        const float* W1 = fw1 + (size_t)l * G_GAUSS * HID_DIM + c;
        float acc[5];
        float bb = fb1[l * HID_DIM + c];
        #pragma unroll
        for (int r = 0; r < 5; r++) acc[r] = bb;
        for (int k = 0; k < G_GAUSS; k++) {
            float wv = W1[k * HID_DIM];
            #pragma unroll
            for (int r = 0; r < 5; r++)
                acc[r] = fmaf(gs_s[rlo + r][k], wv, acc[r]);
        }
        #pragma unroll
        for (int r = 0; r < 5; r++) hid_s[rlo + r][c] = sspf(acc[r]);
    }
    __syncthreads();
    {
        const float* W2 = fw2 + (size_t)l * HID_DIM * HD + c;
        float acc[5];
        float bb = fb2[l * HD + c];
        #pragma unroll
        for (int r = 0; r < 5; r++) acc[r] = bb;
        for (int k = 0; k < HID_DIM; k++) {
            float wv = W2[k * HD];
            #pragma unroll
            for (int r = 0; r < 5; r++)
                acc[r] = fmaf(hid_s[rlo + r][k], wv, acc[r]);
        }
        #pragma unroll
        for (int r = 0; r < 5; r++) {
            float rr = (i0r + rlo + r) * step;
            float C = (rr < 8.0f) ? 0.5f * (cosf(rr * PI_OVER_8) + 1.f) : 0.f;
            wc_s[rlo + r][c] = acc[r] * C;
        }
    }
    __syncthreads();
    for (int j = tid; j < LROWS * HD; j += 256) {
        int r = j >> 7, cc = j & 127;
        unsigned int lo = f2bf(wc_s[r][cc]);
        unsigned int hi = f2bf(wc_s[r + 1][cc]);
        lut[((size_t)l * LUT_ROWS + i0r + r) * HD + cc] = lo | (hi << 16);
    }
    // last block of each layer writes the zeros row (r >= 8 cutoff)
    if (i0r == LUT_T - LROWS && tid < HD)
        lut[((size_t)l * LUT_ROWS + LUT_T) * HD + tid] = 0u;
}

// ------------- histogram + rank (coalesced dst read only) -------------
// rank[e] = arrival index among edges with the same dst -- reuses the
// histogram atomic's return value, so repr_scatter needs NO atomics.
__global__ void repr_hist(const int* __restrict__ dst,
                          int* __restrict__ count,
                          unsigned short* __restrict__ rank) {
    int e = blockIdx.x * blockDim.x + threadIdx.x;
    if (e >= N_EDGES) return;
    rank[e] = (unsigned short)atomicAdd(&count[dst[e]], 1);
}

// ------------- 2-level exclusive scan over 50000 counts -> rowptr -------------
__global__ void repr_scanA(const int* __restrict__ cnt, int* __restrict__ excl,
                           int* __restrict__ bsum) {
    __shared__ int tmp[256];
    int t = threadIdx.x, b = blockIdx.x;
    int i = b * 256 + t;
    int v = (i < N_NODES) ? cnt[i] : 0;
    tmp[t] = v; __syncthreads();
    for (int off = 1; off < 256; off <<= 1) {
        int add = (t >= off) ? tmp[t - off] : 0;
        __syncthreads();
        tmp[t] += add;
        __syncthreads();
    }
    if (i < N_NODES) excl[i] = tmp[t] - v;
    if (t == 255) bsum[b] = tmp[255];
}
__global__ void repr_scanB(const int* __restrict__ bsum, int* __restrict__ bpref) {
    __shared__ int tmp[256];
    int t = threadIdx.x;
    int v = (t < NCHUNK) ? bsum[t] : 0;
    tmp[t] = v; __syncthreads();
    for (int off = 1; off < 256; off <<= 1) {
        int add = (t >= off) ? tmp[t - off] : 0;
        __syncthreads();
        tmp[t] += add;
        __syncthreads();
    }
    if (t < NCHUNK) bpref[t] = tmp[t] - v;
}
__global__ void repr_scanC(const int* __restrict__ excl, const int* __restrict__ bpref,
                           int* __restrict__ rowptr) {
    int i = blockIdx.x * 256 + threadIdx.x;
    if (i < N_NODES) rowptr[i] = excl[i] + bpref[blockIdx.x];
}

// ------------- scatter: compute r + pack + rank-addressed store (atomic-free) ----
__global__ void repr_scatter(const float* __restrict__ R,
                             const int* __restrict__ src, const int* __restrict__ dst,
                             const unsigned short* __restrict__ rank,
                             const int* __restrict__ rowptr,
                             int2* __restrict__ surv) {
    int e = blockIdx.x * blockDim.x + threadIdx.x;
    if (e >= N_EDGES) return;
    int s = src[e], d = dst[e];
    float dx = R[3*s+0] - R[3*d+0];
    float dy = R[3*s+1] - R[3*d+1];
    float dz = R[3*s+2] - R[3*d+2];
    float r = sqrtf(dx*dx + dy*dy + dz*dz);
    // r*2^24; i0 = rf>>16 in [0,2047] for r<8, else 2048 -> zeros row
    unsigned rf = (r < 8.0f) ? (unsigned)(r * 16777216.f) : (2048u << 16);
    if (rf > (2048u << 16)) rf = 2048u << 16;
    surv[rowptr[d] + (int)rank[e]] =
        make_int2((int)((unsigned)s | ((unsigned)d << 16)), (int)rf);
}

// ================= tiled fp32 node GEMMs (64 nodes / block, 256 threads) =================

// agg holds UNNORMALIZED weighted sums; divide by denom[d] here (deferred softmax).
__device__ __forceinline__ void load_ssp_agg(int base, int tid,
        const float* __restrict__ agg, const float* __restrict__ denom,
        float* __restrict__ bufA) {
    int row = tid >> 2;
    int c0 = (tid & 3) << 5;
    int n = base + row;
    float2 dn = *(const float2*)&denom[2 * (size_t)n];
    float i0v = dn.x > 0.f ? 1.f / dn.x : 0.f;
    float i1v = dn.y > 0.f ? 1.f / dn.y : 0.f;
    float inv = (c0 < 64) ? i0v : i1v;
    const float* ap = agg + (size_t)n * HD + c0;
    float* tp = bufA + row * TLD + c0;
    #pragma unroll
    for (int j = 0; j < 8; j++) {
        float4 v = *(const float4*)(ap + j * 4);
        tp[j*4+0] = sspf(v.x * inv); tp[j*4+1] = sspf(v.y * inv);
        tp[j*4+2] = sspf(v.z * inv); tp[j*4+3] = sspf(v.w * inv);
    }
}

__device__ __forceinline__ void gemm_mlp(int base, int tid,
        const float* __restrict__ w1, const float* __restrict__ b1,
        const float* __restrict__ w2, const float* __restrict__ b2,
        float* __restrict__ x, float* __restrict__ bufA, float* __restrict__ v1s)
{
    const int rg = tid >> 4, cg = tid & 15;
    const int r0 = rg * 4, c0 = cg * 4;
    float acc[4][4];
    #pragma unroll
    for (int r = 0; r < 4; r++)
        #pragma unroll
        for (int c = 0; c < 4; c++) acc[r][c] = 0.f;
    for (int k0 = 0; k0 < 128; k0 += 4) {
        float av[4][4];
        #pragma unroll
        for (int r = 0; r < 4; r++)
            *(float4*)av[r] = *(const float4*)&bufA[(r0 + r) * TLD + k0];
        #pragma unroll
        for (int kk = 0; kk < 4; kk++) {
            float4 wv = *(const float4*)(w1 + (k0 + kk) * 64 + c0);
            float wf[4] = {wv.x, wv.y, wv.z, wv.w};
            #pragma unroll
            for (int r = 0; r < 4; r++)
                #pragma unroll
                for (int c = 0; c < 4; c++)
                    acc[r][c] = fmaf(av[r][kk], wf[c], acc[r][c]);
        }
    }
    {
        float4 bv = *(const float4*)(b1 + c0);
        float ba[4] = {bv.x, bv.y, bv.z, bv.w};
        #pragma unroll
        for (int r = 0; r < 4; r++)
            #pragma unroll
            for (int c = 0; c < 4; c++)
                v1s[(r0 + r) * XLD + c0 + c] = sspf(acc[r][c] + ba[c]);
    }
    __syncthreads();
    float acc2[4][4];
    #pragma unroll
    for (int r = 0; r < 4; r++)
        #pragma unroll
        for (int c = 0; c < 4; c++) acc2[r][c] = 0.f;
    for (int k0 = 0; k0 < 64; k0 += 4) {
        float av[4][4];
        #pragma unroll
        for (int r = 0; r < 4; r++)
            *(float4*)av[r] = *(const float4*)&v1s[(r0 + r) * XLD + k0];
        #pragma unroll
        for (int kk = 0; kk < 4; kk++) {
            float4 wv = *(const float4*)(w2 + (k0 + kk) * 64 + c0);
            float wf[4] = {wv.x, wv.y, wv.z, wv.w};
            #pragma unroll
            for (int r = 0; r < 4; r++)
                #pragma unroll
                for (int c = 0; c < 4; c++)
                    acc2[r][c] = fmaf(av[r][kk], wf[c], acc2[r][c]);
        }
    }
    {
        float4 bv = *(const float4*)(b2 + c0);
        #pragma unroll
        for (int r = 0; r < 4; r++) {
            int n = base + r0 + r;
            float4 xv = *(const float4*)(x + (size_t)n * 64 + c0);
            float4 o;
            o.x = acc2[r][0] + bv.x + xv.x;
            o.y = acc2[r][1] + bv.y + xv.y;
            o.z = acc2[r][2] + bv.z + xv.z;
            o.w = acc2[r][3] + bv.w + xv.w;
            *(float4*)&bufA[(r0 + r) * XLD + c0] = o;
            if (n < N_NODES) *(float4*)(x + (size_t)n * 64 + c0) = o;
        }
    }
    __syncthreads();
}

// h stored packed bf16: hq[n*64 + c/2] = bf16(h[c]) | bf16(h[c+1])<<16
__device__ __forceinline__ void gemm_h(int base, int tid,
        const float* __restrict__ bufA,
        const float* __restrict__ fc_w, const float* __restrict__ attn_l,
        const float* __restrict__ attn_r,
        unsigned int* __restrict__ hq, float* __restrict__ el, float* __restrict__ er)
{
    const int rg = tid >> 4, cg = tid & 15;
    const int r0 = rg * 4, c0 = cg * 8;
    float acc[4][8];
    #pragma unroll
    for (int r = 0; r < 4; r++)
        #pragma unroll
        for (int c = 0; c < 8; c++) acc[r][c] = 0.f;
    for (int k0 = 0; k0 < 64; k0 += 4) {
        float av[4][4];
        #pragma unroll
        for (int r = 0; r < 4; r++)
            *(float4*)av[r] = *(const float4*)&bufA[(r0 + r) * XLD + k0];
        #pragma unroll
        for (int kk = 0; kk < 4; kk++) {
            float4 w0 = *(const float4*)(fc_w + (k0 + kk) * 128 + c0);
            float4 w1v = *(const float4*)(fc_w + (k0 + kk) * 128 + c0 + 4);
            float wf[8] = {w0.x, w0.y, w0.z, w0.w, w1v.x, w1v.y, w1v.z, w1v.w};
            #pragma unroll
            for (int r = 0; r < 4; r++)
                #pragma unroll
                for (int c = 0; c < 8; c++)
                    acc[r][c] = fmaf(av[r][kk], wf[c], acc[r][c]);
        }
    }
    float al[8], ar[8];
    #pragma unroll
    for (int c = 0; c < 8; c++) { al[c] = attn_l[c0 + c]; ar[c] = attn_r[c0 + c]; }
    int head = cg >> 3;
    #pragma unroll
    for (int r = 0; r < 4; r++) {
        int n = base + r0 + r;
        float pel = 0.f, per = 0.f;
        #pragma unroll
        for (int c = 0; c < 8; c++) {
            pel = fmaf(acc[r][c], al[c], pel);
            per = fmaf(acc[r][c], ar[c], per);
        }
        if (n < N_NODES) {
            uint4 pv;
            pv.x = (unsigned int)f2bf(acc[r][0]) | ((unsigned int)f2bf(acc[r][1]) << 16);
            pv.y = (unsigned int)f2bf(acc[r][2]) | ((unsigned int)f2bf(acc[r][3]) << 16);
            pv.z = (unsigned int)f2bf(acc[r][4]) | ((unsigned int)f2bf(acc[r][5]) << 16);
            pv.w = (unsigned int)f2bf(acc[r][6]) | ((unsigned int)f2bf(acc[r][7]) << 16);
            *(uint4*)(hq + (size_t)n * 64 + cg * 4) = pv;
        }
        #pragma unroll
        for (int off = 1; off < 8; off <<= 1) {
            pel += __shfl_xor(pel, off, 64);
            per += __shfl_xor(per, off, 64);
        }
        if ((cg & 7) == 0 && n < N_NODES) {
            el[n * 2 + head] = pel;
            er[n * 2 + head] = per;
        }
    }
}

__global__ __launch_bounds__(256) void repr_embed_h(
        const float* __restrict__ emb, const int* __restrict__ Z,
        const float* __restrict__ fc_w, const float* __restrict__ attn_l,
        const float* __restrict__ attn_r,
        float* __restrict__ x, unsigned int* __restrict__ hq,
        float* __restrict__ el, float* __restrict__ er) {
    __shared__ float bufA[TN * XLD];
    int base = blockIdx.x * TN, tid = threadIdx.x;
    int row = tid >> 2;
    int c0 = (tid & 3) << 4;
    int n = base + row;
    int z = (n < N_NODES) ? Z[n] : 0;
    const float* ep = emb + (size_t)z * D_DIM + c0;
    float* bp = bufA + row * XLD + c0;
    #pragma unroll
    for (int j = 0; j < 4; j++) {
        float4 v = *(const float4*)(ep + j * 4);
        *(float4*)(bp + j * 4) = v;
        if (n < N_NODES) *(float4*)(x + (size_t)n * D_DIM + c0 + j * 4) = v;
    }
    __syncthreads();
    gemm_h(base, tid, bufA, fc_w, attn_l, attn_r, hq, el, er);
}

__global__ __launch_bounds__(256) void repr_mlp_h(
        const float* __restrict__ agg, const float* __restrict__ denom,
        const float* __restrict__ w1, const float* __restrict__ b1,
        const float* __restrict__ w2, const float* __restrict__ b2,
        const float* __restrict__ fc_w, const float* __restrict__ attn_l,
        const float* __restrict__ attn_r,
        float* __restrict__ x, unsigned int* __restrict__ hq,
        float* __restrict__ el, float* __restrict__ er) {
    __shared__ float bufA[TN * TLD];
    __shared__ float v1s[TN * XLD];
    int base = blockIdx.x * TN, tid = threadIdx.x;
    load_ssp_agg(base, tid, agg, denom, bufA);
    __syncthreads();
    gemm_mlp(base, tid, w1, b1, w2, b2, x, bufA, v1s);
    gemm_h(base, tid, bufA, fc_w, attn_l, attn_r, hq, el, er);
}

__global__ __launch_bounds__(256) void repr_mlp_out(
        const float* __restrict__ agg, const float* __restrict__ denom,
        const float* __restrict__ w1, const float* __restrict__ b1,
        const float* __restrict__ w2, const float* __restrict__ b2,
        const float* __restrict__ ow1, const float* __restrict__ ob1,
        const float* __restrict__ ow2, const float* __restrict__ ob2,
        float* __restrict__ x, float* __restrict__ hh) {
    __shared__ float bufA[TN * TLD];
    __shared__ float v1s[TN * XLD];
    int base = blockIdx.x * TN, tid = threadIdx.x;
    load_ssp_agg(base, tid, agg, denom, bufA);
    __syncthreads();
    gemm_mlp(base, tid, w1, b1, w2, b2, x, bufA, v1s);
    const int rg = tid >> 4, cg = tid & 15;
    const int r0 = rg * 4, c0 = cg * 8;
    float acc[4][8];
    #pragma unroll
    for (int r = 0; r < 4; r++)
        #pragma unroll
        for (int c = 0; c < 8; c++) acc[r][c] = 0.f;
    for (int k0 = 0; k0 < 64; k0 += 4) {
        float av[4][4];
        #pragma unroll
        for (int r = 0; r < 4; r++)
            *(float4*)av[r] = *(const float4*)&bufA[(r0 + r) * XLD + k0];
        #pragma unroll
        for (int kk = 0; kk < 4; kk++) {
            float4 w0 = *(const float4*)(ow1 + (k0 + kk) * 128 + c0);
            float4 w1v = *(const float4*)(ow1 + (k0 + kk) * 128 + c0 + 4);
            float wf[8] = {w0.x, w0.y, w0.z, w0.w, w1v.x, w1v.y, w1v.z, w1v.w};
            #pragma unroll
            for (int r = 0; r < 4; r++)
                #pragma unroll
                for (int c = 0; c < 8; c++)
                    acc[r][c] = fmaf(av[r][kk], wf[c], acc[r][c]);
        }
    }
    float o1[8], w2c[8];
    #pragma unroll
    for (int c = 0; c < 8; c++) { o1[c] = ob1[c0 + c]; w2c[c] = ow2[c0 + c]; }
    #pragma unroll
    for (int r = 0; r < 4; r++) {
        int n = base + r0 + r;
        float s = 0.f;
        #pragma unroll
        for (int c = 0; c < 8; c++)
            s = fmaf(sspf(acc[r][c] + o1[c]), w2c[c], s);
        #pragma unroll
        for (int off = 1; off < 16; off <<= 1)
            s += __shfl_xor(s, off, 64);
        if (cg == 0 && n < N_NODES) hh[n] = s + ob2[0];
    }
}

// ------------- LUT message, dual-stream: 2 independent subranges per thread -------
// TILE=512 edges; 256 threads = 64 col-pairs x 4 wave-slots; each thread walks
// TWO independent 64-edge subranges (sp and sp+4) interleaved in one loop,
// doubling in-flight gathers at fixed occupancy. Subranges remain 64-edge
// aligned globally, so the atomic-boundary row set (repr_zero_b) is unchanged.
// Last tile has nc=256 (multiple of 64): stream B inert (block-uniform guard).
// Denominator: segment-head rows sum staged exps per dst-run, one global
// atomicAdd pair per (segment, tile).
#define TILE 512
__global__ __launch_bounds__(256) void repr_msg_lut(
    const int2* __restrict__ surv,
    const float* __restrict__ el, const float* __restrict__ er,
    const unsigned int* __restrict__ hq,
    const unsigned int* __restrict__ lut,
    float* __restrict__ agg, float* __restrict__ denom)
{
    __shared__ int4 rowinfo[TILE];     // {lut row i0, src, dst, frac bits}
    __shared__ float scl[TILE][2];     // exp(leaky(el+er)) per head
    int base = blockIdx.x * TILE;
    int nc = N_EDGES - base; if (nc > TILE) nc = TILE;
    int tid = threadIdx.x;
    for (int j = tid; j < nc; j += 256) {
        int2 ev = surv[base + j];
        int sn = (int)((unsigned)ev.x & 0xFFFFu);
        int d  = (int)((unsigned)ev.x >> 16);
        unsigned rf = (unsigned)ev.y;
        int i0 = (int)(rf >> 16);
        float fr = (float)(rf & 0xFFFFu) * (1.f / 65536.f);
        float2 a = *(const float2*)&el[2 * sn];
        float2 b = *(const float2*)&er[2 * d];
        float v0 = a.x + b.x; v0 = v0 >= 0.f ? v0 : 0.2f * v0;
        float v1 = a.y + b.y; v1 = v1 >= 0.f ? v1 : 0.2f * v1;
        rowinfo[j] = make_int4(i0, sn, d, __float_as_int(fr));
        scl[j][0] = __expf(v0); scl[j][1] = __expf(v1);
    }
    __syncthreads();
    // segment-head rows accumulate this tile's denom contribution
    for (int j = tid; j < nc; j += 256) {
        int dj = rowinfo[j].z;
        bool headl = (j == 0) || (rowinfo[j - 1].z != dj);
        if (headl) {
            float s0 = scl[j][0], s1 = scl[j][1];
            for (int r = j + 1; r < nc && rowinfo[r].z == dj; r++) {
                s0 += scl[r][0]; s1 += scl[r][1];
            }
            atomicAdd(&denom[2 * dj], s0);
            atomicAdd(&denom[2 * dj + 1], s1);
        }
    }
    const int cp = tid & 63;           // col pair: cols 2cp, 2cp+1
    const int sp = tid >> 6;
    const int head = cp >> 5;          // cols 0-63 head0, 64-127 head1
    const int loA = sp * 64;
    const int loB = (sp + 4) * 64;
    const bool hasB = loB < nc;        // block-uniform (nc==512 except last tile)
    const uint2* __restrict__ l2p = (const uint2*)lut;
    float a0 = 0.f, a1 = 0.f, b0 = 0.f, b1 = 0.f;
    int curA = -1, curB = -1;
    int fsA = 1, fsB = 1;
    #pragma unroll 2
    for (int j = 0; j < 64; j++) {
        {   // ---- stream A ----
            int r = loA + j;
            int4 ri = rowinfo[r];
            if (ri.z != curA) {
                if (curA >= 0) {
                    float* ap = &agg[(size_t)curA * HD + 2 * cp];
                    if (fsA) { atomicAdd(ap, a0); atomicAdd(ap + 1, a1); }
                    else *(float2*)ap = make_float2(a0, a1);
                }
                curA = ri.z; a0 = 0.f; a1 = 0.f; fsA = (j == 0);
            }
            uint2 tv = l2p[(size_t)ri.x * 64 + cp];
            unsigned int hv = hq[(size_t)ri.y * 64 + cp];
            float fr = __int_as_float(ri.w);
            float s = scl[r][head];
            float wa0 = __uint_as_float(tv.x << 16);
            float wa1 = __uint_as_float(tv.x & 0xFFFF0000u);
            float wb0 = __uint_as_float(tv.y << 16);
            float wb1 = __uint_as_float(tv.y & 0xFFFF0000u);
            float ha = __uint_as_float(hv << 16);
            float hb = __uint_as_float(hv & 0xFFFF0000u);
            float wa = fmaf(fr, wa1 - wa0, wa0);
            float wb = fmaf(fr, wb1 - wb0, wb0);
            a0 = fmaf(wa * ha, s, a0);
            a1 = fmaf(wb * hb, s, a1);
        }
        if (hasB) {   // ---- stream B ----
            int r = loB + j;
            int4 ri = rowinfo[r];
            if (ri.z != curB) {
                if (curB >= 0) {
                    float* ap = &agg[(size_t)curB * HD + 2 * cp];
                    if (fsB) { atomicAdd(ap, b0); atomicAdd(ap + 1, b1); }
                    else *(float2*)ap = make_float2(b0, b1);
                }
                curB = ri.z; b0 = 0.f; b1 = 0.f; fsB = (j == 0);
            }
            uint2 tv = l2p[(size_t)ri.x * 64 + cp];
            unsigned int hv = hq[(size_t)ri.y * 64 + cp];
            float fr = __int_as_float(ri.w);
            float s = scl[r][head];
            float wa0 = __uint_as_float(tv.x << 16);
            float wa1 = __uint_as_float(tv.x & 0xFFFF0000u);
            float wb0 = __uint_as_float(tv.y << 16);
            float wb1 = __uint_as_float(tv.y & 0xFFFF0000u);
            float ha = __uint_as_float(hv << 16);
            float hb = __uint_as_float(hv & 0xFFFF0000u);
            float wa = fmaf(fr, wa1 - wa0, wa0);
            float wb = fmaf(fr, wb1 - wb0, wb0);
            b0 = fmaf(wa * ha, s, b0);
            b1 = fmaf(wb * hb, s, b1);
        }
    }
    // trailing segments may continue into next subrange/tile -> atomic
    if (curA >= 0) {
        float* ap = &agg[(size_t)curA * HD + 2 * cp];
        atomicAdd(ap, a0); atomicAdd(ap + 1, a1);
    }
    if (hasB && curB >= 0) {
        float* ap = &agg[(size_t)curB * HD + 2 * cp];
        atomicAdd(ap, b0); atomicAdd(ap + 1, b1);
    }
}

// ------------- graph segment-sum with LDS privatization -> d_out directly -------------
__global__ void repr_gsum(const float* __restrict__ hh, const int* __restrict__ gids,
                          float* __restrict__ dout) {
    __shared__ float bins[B_GRAPHS];
    int t = threadIdx.x;
    if (t < B_GRAPHS) bins[t] = 0.f;
    __syncthreads();
    int i = blockIdx.x * 256 + t;
    if (i < N_NODES) atomicAdd(&bins[gids[i]], hh[i]);
    __syncthreads();
    if (t < B_GRAPHS && bins[t] != 0.f) atomicAdd(&dout[t], bins[t]);
}

extern "C" void kernel_launch(void* const* d_in, const int* in_sizes, int n_in,
                              void* d_out, int out_size, void* d_ws, size_t ws_size,
                              hipStream_t stream) {
    (void)in_sizes; (void)n_in; (void)out_size; (void)ws_size;
    const float* R      = (const float*)d_in[0];
    const int*   Z      = (const int*)d_in[1];
    const int*   src    = (const int*)d_in[2];
    const int*   dst    = (const int*)d_in[3];
    const int*   gids   = (const int*)d_in[4];
    const float* emb    = (const float*)d_in[5];
    const float* offs   = (const float*)d_in[6];
    const float* widths = (const float*)d_in[7];
    const float* fc_w   = (const float*)d_in[8];
    const float* attn_l = (const float*)d_in[9];
    const float* attn_r = (const float*)d_in[10];
    const float* fw1    = (const float*)d_in[11];
    const float* fb1    = (const float*)d_in[12];
    const float* fw2    = (const float*)d_in[13];
    const float* fb2    = (const float*)d_in[14];
    const float* mw1    = (const float*)d_in[15];
    const float* mb1    = (const float*)d_in[16];
    const float* mw2    = (const float*)d_in[17];
    const float* mb2    = (const float*)d_in[18];
    const float* ow1    = (const float*)d_in[19];
    const float* ob1    = (const float*)d_in[20];
    const float* ow2    = (const float*)d_in[21];
    const float* ob2    = (const float*)d_in[22];

    char* p = (char*)d_ws;
    float* x      = (float*)p; p += (size_t)N_NODES * 64 * 4;
    unsigned int* hq = (unsigned int*)p; p += (size_t)N_NODES * 64 * 4;  // packed bf16 pairs
    float* el     = (float*)p; p += (size_t)N_NODES * 2 * 4;
    float* er     = (float*)p; p += (size_t)N_NODES * 2 * 4;
    float* denom  = (float*)p; p += (size_t)N_NODES * 2 * 4;
    float* agg    = (float*)p; p += (size_t)N_NODES * 128 * 4;
    int2*  surv   = (int2*)p;  p += (size_t)N_EDGES * 8;
    unsigned int* lut = (unsigned int*)p; p += (size_t)L_LAYERS * LUT_ROWS * HD * 4;
    float* hh     = (float*)p; p += (size_t)N_NODES * 4;
    int*   bsum   = (int*)p;   p += 1024;
    int*   bpref  = (int*)p;   p += 1024;
    // scan/scatter temporaries aliased into x (x written by repr_embed_h, strictly
    // after repr_scatter in stream order):
    int* count = (int*)x;                                        // 200 KB
    int* excl  = (int*)((char*)x + 256 * 1024);                  // 200 KB
    unsigned short* rank = (unsigned short*)((char*)x + 512 * 1024);   // 1.6 MB
    int* rowptr = (int*)((char*)x + 2560 * 1024);                // 200 KB

    // one-time prep: zero edge counter + d_out
    repr_prep<<<(N_NODES + B_GRAPHS + 255) / 256, 256, 0, stream>>>(
        count, (float*)d_out);
    repr_hist<<<N_EDGES / 256, 256, 0, stream>>>(dst, count, rank);
    repr_scanA<<<NCHUNK, 256, 0, stream>>>(count, excl, bsum);
    repr_scanB<<<1, 256, 0, stream>>>(bsum, bpref);
    repr_scanC<<<NCHUNK, 256, 0, stream>>>(excl, bpref, rowptr);
    repr_scatter<<<N_EDGES / 256, 256, 0, stream>>>(
        R, src, dst, rank, rowptr, surv);

    // build the w(r)*C(r) tables
    repr_lut_build<<<L_LAYERS * (LUT_T / LROWS), 256, 0, stream>>>(
        offs, widths, fw1, fb1, fw2, fb2, lut);

    repr_embed_h<<<NBLK, 256, 0, stream>>>(
        emb, Z, fc_w, attn_l, attn_r, x, hq, el, er);

    for (int l = 0; l < L_LAYERS; l++) {
        repr_zero_b<<<(ZB_T + 255) / 256, 256, 0, stream>>>(surv, agg, denom);
        repr_msg_lut<<<(N_EDGES + TILE - 1) / TILE, 256, 0, stream>>>(
            surv, el, er, hq, lut + (size_t)l * LUT_ROWS * HD, agg, denom);
        if (l < L_LAYERS - 1) {
            repr_mlp_h<<<NBLK, 256, 0, stream>>>(
                agg, denom, mw1 + (size_t)l * 128 * 64, mb1 + l * 64,
                mw2 + (size_t)l * 64 * 64, mb2 + l * 64,
                fc_w + (size_t)(l + 1) * 64 * 128, attn_l + (l + 1) * 128,
                attn_r + (l + 1) * 128, x, hq, el, er);
        } else {
            repr_mlp_out<<<NBLK, 256, 0, stream>>>(
                agg, denom, mw1 + (size_t)l * 128 * 64, mb1 + l * 64,
                mw2 + (size_t)l * 64 * 64, mb2 + l * 64,
                ow1, ob1, ow2, ob2, x, hh);
        }
    }
    repr_gsum<<<NCHUNK, 256, 0, stream>>>(hh, gids, (float*)d_out);
}